// Round 13
// baseline (280.192 us; speedup 1.0000x reference)
//
#include <hip/hip_runtime.h>
#include <hip/hip_bf16.h>

// Problem constants (match reference)
#define B_ 2
#define T_ 2048
#define D_ 2048
#define H_ 16
#define G_ 4
#define HD_ 128
#define GS_ (H_/G_)

typedef _Float16 half8 __attribute__((ext_vector_type(8)));
typedef _Float16 half2_t __attribute__((ext_vector_type(2)));
typedef float f32x4 __attribute__((ext_vector_type(4)));
typedef float f32x16 __attribute__((ext_vector_type(16)));
typedef int int4_t __attribute__((ext_vector_type(4)));

// Combined KV tile image (32-key tiles): per (b,g,tile32):
//   [K: 32 rows x 136 f16 (128 data + 8 pad)]  = 8704 B
//   [V^T: 128 rows x 40 f16 (32 data + 8 pad)] = 10240 B
// padded to 20480 B (20 x 1024B groups -> each of 4 waves stages exactly 5).
#define KV_TILE_BYTES 20480
#define KROW_F16 136
#define VROW_F16 40
#define VBASE_F16 4352   // 8704 bytes / 2

// ---------------- fused vectorized fp32 -> fp16 conversion (x, Wq, Wk, Wv, Wo) ----------------
#define C0_ 1048576   // x:  8388608/8
#define C1_ 1572864   // +Wq 4194304/8
#define C2_ 1703936   // +Wk 1048576/8
#define C3_ 1835008   // +Wv 1048576/8
#define C4_ 2359296   // +Wo 4194304/8
__global__ void cvt_all(const float* __restrict__ sx, const float* __restrict__ sq,
                        const float* __restrict__ sk, const float* __restrict__ sv,
                        const float* __restrict__ so,
                        _Float16* __restrict__ dx, _Float16* __restrict__ dq,
                        _Float16* __restrict__ dk, _Float16* __restrict__ dv,
                        _Float16* __restrict__ dw) {
    int g = blockIdx.x * blockDim.x + threadIdx.x;
    int stride = blockDim.x * gridDim.x;
    for (; g < C4_; g += stride) {
        const float* src; _Float16* dst; int local;
        if (g < C0_)      { src = sx; dst = dx; local = g; }
        else if (g < C1_) { src = sq; dst = dq; local = g - C0_; }
        else if (g < C2_) { src = sk; dst = dk; local = g - C1_; }
        else if (g < C3_) { src = sv; dst = dv; local = g - C2_; }
        else              { src = so; dst = dw; local = g - C3_; }
        f32x4 a = *((const f32x4*)src + local * 2);
        f32x4 b = *((const f32x4*)src + local * 2 + 1);
        half8 hv;
        hv[0] = (_Float16)a[0]; hv[1] = (_Float16)a[1];
        hv[2] = (_Float16)a[2]; hv[3] = (_Float16)a[3];
        hv[4] = (_Float16)b[0]; hv[5] = (_Float16)b[1];
        hv[6] = (_Float16)b[2]; hv[7] = (_Float16)b[3];
        *((half8*)dst + local) = hv;
    }
}

// ---------------- RoPE tables: cos/sin (T_, 64) ----------------
__global__ void rope_tables_k(float* __restrict__ cosT, float* __restrict__ sinT) {
    int i = blockIdx.x * blockDim.x + threadIdx.x; // T_*64 threads
    int t = i >> 6, l = i & 63;
    float inv_freq = powf(10000.0f, -((float)(2 * l)) / 128.0f);
    float a = (float)t * inv_freq;
    cosT[i] = cosf(a);
    sinT[i] = sinf(a);
}

// ---------------- Tiled TN GEMM, 128x128 tile, 2-deep counted-vmcnt pipeline ----------------
__global__ void __launch_bounds__(256) gemm_tile(const _Float16* __restrict__ A,
                                                 const _Float16* __restrict__ B0,
                                                 float* __restrict__ C0, int n0t,
                                                 const _Float16* __restrict__ B1,
                                                 float* __restrict__ C1, int n1t,
                                                 const _Float16* __restrict__ B2,
                                                 float* __restrict__ C2, int n2t,
                                                 int Kd) {
    __shared__ _Float16 sA[2][128 * 32];
    __shared__ _Float16 sB[2][128 * 32];

    int tid = threadIdx.x;
    int w = tid >> 6, lane = tid & 63;
    int l15 = lane & 15, g4 = lane >> 4;
    int wm = w >> 1, wn = w & 1;

    int y = blockIdx.y;
    const _Float16* Bsel;
    float* Csel;
    int ldc, cb;
    if (y < n0t)            { Bsel = B0; Csel = C0; ldc = n0t * 128; cb = y; }
    else if (y < n0t + n1t) { Bsel = B1; Csel = C1; ldc = n1t * 128; cb = y - n0t; }
    else                    { Bsel = B2; Csel = C2; ldc = n2t * 128; cb = y - n0t - n1t; }

    const _Float16* Ab = A + (size_t)(blockIdx.x * 128) * Kd;
    const _Float16* Bb = Bsel + (size_t)(cb * 128) * Kd;

    int s0 = w * 128 + lane;
    int s1 = s0 + 64;
    size_t ga0 = (size_t)(s0 >> 2) * Kd + (s0 & 3) * 8;
    size_t ga1 = (size_t)(s1 >> 2) * Kd + (s1 & 3) * 8;

    #define STAGE(BUF, K0)                                                                     \
        do {                                                                                   \
            _Float16* a0_ = &sA[BUF][0] + (size_t)(w * 2) * 512;                               \
            _Float16* a1_ = &sA[BUF][0] + (size_t)(w * 2 + 1) * 512;                           \
            _Float16* b0_ = &sB[BUF][0] + (size_t)(w * 2) * 512;                               \
            _Float16* b1_ = &sB[BUF][0] + (size_t)(w * 2 + 1) * 512;                           \
            __builtin_amdgcn_global_load_lds(                                                  \
                (const __attribute__((address_space(1))) unsigned int*)(Ab + ga0 + (K0)),      \
                (__attribute__((address_space(3))) unsigned int*)a0_, 16, 0, 0);               \
            __builtin_amdgcn_global_load_lds(                                                  \
                (const __attribute__((address_space(1))) unsigned int*)(Ab + ga1 + (K0)),      \
                (__attribute__((address_space(3))) unsigned int*)a1_, 16, 0, 0);               \
            __builtin_amdgcn_global_load_lds(                                                  \
                (const __attribute__((address_space(1))) unsigned int*)(Bb + ga0 + (K0)),      \
                (__attribute__((address_space(3))) unsigned int*)b0_, 16, 0, 0);               \
            __builtin_amdgcn_global_load_lds(                                                  \
                (const __attribute__((address_space(1))) unsigned int*)(Bb + ga1 + (K0)),      \
                (__attribute__((address_space(3))) unsigned int*)b1_, 16, 0, 0);               \
        } while (0)

    f32x4 acc[4][4];
    #pragma unroll
    for (int i = 0; i < 4; i++)
        #pragma unroll
        for (int j = 0; j < 4; j++) acc[i][j] = (f32x4){0.f, 0.f, 0.f, 0.f};

    int nIt = Kd >> 5;
    STAGE(0, 0);
    if (nIt > 1) STAGE(1, 32);

    for (int it = 0; it < nIt; ++it) {
        int cur = it & 1;
        if (it + 1 < nIt) asm volatile("s_waitcnt vmcnt(4)" ::: "memory");
        else              asm volatile("s_waitcnt vmcnt(0)" ::: "memory");
        __builtin_amdgcn_sched_barrier(0);
        __builtin_amdgcn_s_barrier();          // all waves' tile-it loads landed
        __builtin_amdgcn_sched_barrier(0);

        half8 af[4], bf[4];
        #pragma unroll
        for (int mi = 0; mi < 4; mi++)
            af[mi] = *(const half8*)&sA[cur][(wm * 64 + mi * 16 + l15) * 32 + g4 * 8];
        #pragma unroll
        for (int ni = 0; ni < 4; ni++)
            bf[ni] = *(const half8*)&sB[cur][(wn * 64 + ni * 16 + l15) * 32 + g4 * 8];

        #pragma unroll
        for (int mi = 0; mi < 4; mi++)
            #pragma unroll
            for (int ni = 0; ni < 4; ni++)
                acc[mi][ni] = __builtin_amdgcn_mfma_f32_16x16x32_f16(af[mi], bf[ni], acc[mi][ni], 0, 0, 0);

        __builtin_amdgcn_sched_barrier(0);
        asm volatile("" ::: "memory");         // pin LDS reads above the barrier
        __builtin_amdgcn_s_barrier();          // all waves done reading buf[cur]
        __builtin_amdgcn_sched_barrier(0);
        if (it + 2 < nIt) STAGE(cur, (size_t)(it + 2) * 32);
    }
    #undef STAGE

    int rbase = blockIdx.x * 128 + wm * 64 + g4 * 4;
    int cbase = cb * 128 + wn * 64 + l15;
    #pragma unroll
    for (int mi = 0; mi < 4; mi++)
        #pragma unroll
        for (int r = 0; r < 4; r++) {
            float* crow = Csel + (size_t)(rbase + mi * 16 + r) * ldc + cbase;
            #pragma unroll
            for (int ni = 0; ni < 4; ni++) crow[ni * 16] = acc[mi][ni][r];
        }
}

// ---------------- fused RMSNorm + RoPE (Q and K in one dispatch) ----------------
// Q scale folds BOTH the attention score scale (1/128) and log2(e) so attention
// scores come out in the log2 domain (softmax uses exp2 directly).
__global__ void rmsnorm_rope_qk(float* __restrict__ Qf, float* __restrict__ Kf,
                                const float* __restrict__ qw, const float* __restrict__ kw,
                                const float* __restrict__ cosT, const float* __restrict__ sinT,
                                _Float16* __restrict__ qH) {
    int gw = (int)((blockIdx.x * (size_t)blockDim.x + threadIdx.x) >> 6);
    int lane = threadIdx.x & 63;
    bool isQ = gw < (B_ * T_ * H_);
    int row_i = isQ ? gw : gw - (B_ * T_ * H_);
    int heads = isQ ? H_ : G_;
    const float* wv = isQ ? qw : kw;
    float* row = (isQ ? Qf : Kf) + (size_t)row_i * HD_;
    int t = (row_i / heads) % T_;
    float x0 = row[lane];
    float x1 = row[lane + 64];
    float ss = x0 * x0 + x1 * x1;
    #pragma unroll
    for (int off = 1; off < 64; off <<= 1) ss += __shfl_xor(ss, off);
    float inv = rsqrtf(ss * (1.0f / 128.0f) + 1e-6f);
    float n0 = x0 * inv * wv[lane];
    float n1 = x1 * inv * wv[lane + 64];
    float c = cosT[t * 64 + lane];
    float s = sinT[t * 64 + lane];
    float r0 = n0 * c - n1 * s;
    float r1 = n1 * c + n0 * s;
    if (isQ) {
        const float QSCL = 1.44269504089f / 128.0f;   // log2(e) * (1/HD)
        qH[(size_t)row_i * HD_ + lane]      = (_Float16)(r0 * QSCL);
        qH[(size_t)row_i * HD_ + lane + 64] = (_Float16)(r1 * QSCL);
    } else {
        row[lane]      = r0;
        row[lane + 64] = r1;
    }
}

// ---------------- pack K+V into combined padded f16 tile image (32-key tiles) ----------------
// Grid: 512 blocks = (b,g,tile32); 256 threads.
__global__ void __launch_bounds__(256) pack_kv(const float* __restrict__ kf,
                                               const float* __restrict__ vf,
                                               _Float16* __restrict__ img) {
    int bid = blockIdx.x;
    int tile = bid & 63, g = (bid >> 6) & 3, b = bid >> 8;
    int tid = threadIdx.x;
    _Float16* out = img + (size_t)bid * (KV_TILE_BYTES / 2);

    // K part: 32 rows x 17 granules (granule 16 = pad) = 544 granules
    #pragma unroll
    for (int it = 0; it < 3; it++) {
        int gi = tid + 256 * it;
        if (gi < 32 * 17) {
            int key = gi / 17, gr = gi % 17;
            half8 hv = (half8){0, 0, 0, 0, 0, 0, 0, 0};
            if (gr < 16) {
                const float* src = kf + ((size_t)((b * T_ + tile * 32 + key) * G_ + g)) * HD_ + gr * 8;
                #pragma unroll
                for (int j = 0; j < 8; j++) hv[j] = (_Float16)src[j];
            }
            *(half8*)(out + (size_t)gi * 8) = hv;
        }
    }
    // V^T part: 128 rows (d) x 5 granules (granule 4 = pad) = 640 granules
    #pragma unroll
    for (int it = 0; it < 3; it++) {
        int vi = tid + 256 * it;
        if (vi < 128 * 5) {
            int d = vi / 5, gr = vi % 5;
            half8 hv = (half8){0, 0, 0, 0, 0, 0, 0, 0};
            if (gr < 4) {
                const float* src = vf + ((size_t)((b * T_ + tile * 32 + gr * 8) * G_ + g)) * HD_ + d;
                #pragma unroll
                for (int j = 0; j < 8; j++) hv[j] = (_Float16)src[(size_t)j * (G_ * HD_)];
            }
            *(half8*)(out + VBASE_F16 + (size_t)vi * 8) = hv;
        }
    }
}

// ---------------- causal GQA flash attention v8 ----------------
// v5-verified structure, 32-key tiles for 2x occupancy (4 blocks/CU, 4 waves/SIMD):
// 32x32x16 MFMA, swapped QK^T, in-register log2-domain softmax (exp2, verified R11),
// defer-max thr 11.5, counted-vmcnt 2-deep staging (5 loads/wave/tile).
__global__ void __launch_bounds__(256, 4) attn_mfma8(const _Float16* __restrict__ qh,
                                                     const _Float16* __restrict__ kvimg,
                                                     _Float16* __restrict__ ctx) {
    int id = blockIdx.x;
    int hlf = id >> 8, rr0 = id & 255;
    int qb = hlf ? (15 - (rr0 & 15)) : (rr0 & 15);
    int hb = (rr0 >> 4) | (hlf << 4);
    int h = hb & 15, b = hb >> 4;
    int g = h >> 2;

    int tid = threadIdx.x;
    int w = tid >> 6, lane = tid & 63;
    int l31 = lane & 31, hi = lane >> 5;

    __shared__ __align__(16) char sKV[2][KV_TILE_BYTES];   // 40 KB total

    int qW = qb * 128 + w * 32;
    int qme = qW + l31;

    half8 qfrag[8];
    {
        const _Float16* qrow = qh + ((size_t)(b * T_ + qme)) * (H_ * HD_) + h * HD_ + hi * 8;
        #pragma unroll
        for (int ks = 0; ks < 8; ks++) qfrag[ks] = *(const half8*)(qrow + ks * 16);
    }

    f32x16 o[4];
    #pragma unroll
    for (int dt2 = 0; dt2 < 4; dt2++)
        #pragma unroll
        for (int r = 0; r < 16; r++) o[dt2][r] = 0.f;
    float m = -INFINITY, lsum = 0.f;

    const char* ibase = (const char*)kvimg + (size_t)((b * 4 + g) * 64) * KV_TILE_BYTES;

    // 20 groups of 1024B per tile; wave w takes groups w, w+4, ..., w+16 (5 each)
    #define STAGE_T(BUF, KT)                                                                       \
        do {                                                                                       \
            const char* src_ = ibase + (size_t)(KT) * KV_TILE_BYTES;                               \
            char* dst_ = &sKV[BUF][0];                                                             \
            _Pragma("unroll")                                                                      \
            for (int i_ = 0; i_ < 5; i_++) {                                                       \
                int c_ = w + 4 * i_;                                                               \
                __builtin_amdgcn_global_load_lds(                                                  \
                    (const __attribute__((address_space(1))) unsigned int*)(src_ + c_ * 1024 + lane * 16), \
                    (__attribute__((address_space(3))) unsigned int*)(dst_ + c_ * 1024 + lane * 16), 16, 0, 0); \
            }                                                                                      \
        } while (0)

    int nt = 4 * qb + 4;
    int ktmax_w = (qW + 31) >> 5;

    STAGE_T(0, 0);
    STAGE_T(1, 1);      // nt >= 4 always

    for (int kt = 0; kt < nt; kt++) {
        int cur = kt & 1;
        if (kt + 1 < nt) asm volatile("s_waitcnt vmcnt(5)" ::: "memory");
        else             asm volatile("s_waitcnt vmcnt(0)" ::: "memory");
        __builtin_amdgcn_sched_barrier(0);
        __builtin_amdgcn_s_barrier();      // all waves' tile-kt loads landed
        __builtin_amdgcn_sched_barrier(0);

        if (kt <= ktmax_w) {
            const char* bufK = &sKV[cur][0];
            const char* bufV = &sKV[cur][0] + VBASE_F16 * 2;

            // ---- swapped QK^T (scores in log2 domain via Q scale) ----
            f32x16 stc;
            #pragma unroll
            for (int r = 0; r < 16; r++) stc[r] = 0.f;

            __builtin_amdgcn_s_setprio(1);
            #pragma unroll
            for (int ks = 0; ks < 8; ks++) {
                half8 kfr = *(const half8*)(bufK + l31 * (KROW_F16 * 2) + ks * 32 + hi * 16);
                stc = __builtin_amdgcn_mfma_f32_32x32x16_f16(kfr, qfrag[ks], stc, 0, 0, 0);
            }
            __builtin_amdgcn_s_setprio(0);

            // ---- causal mask ----
            #pragma unroll
            for (int reg = 0; reg < 16; reg++) {
                int key = kt * 32 + 8 * (reg >> 2) + 4 * hi + (reg & 3);
                float v = stc[reg];
                stc[reg] = (key <= qme) ? v : -INFINITY;
            }

            // ---- in-lane max + cross-half combine ----
            float pmax = -INFINITY;
            #pragma unroll
            for (int reg = 0; reg < 16; reg++) pmax = fmaxf(pmax, stc[reg]);
            pmax = fmaxf(pmax, __shfl_xor(pmax, 32));

            // ---- defer-max rescale (thr 11.5 in log2 domain ~ e^8) ----
            if (__any(!(pmax - m <= 11.5f))) {
                float nm = fmaxf(m, pmax);
                float alpha = __builtin_exp2f(m - nm);   // first tile: 2^-inf = 0
                lsum *= alpha;
                #pragma unroll
                for (int reg = 0; reg < 16; reg++) {
                    float ar = __shfl(alpha, 8 * (reg >> 2) + 4 * hi + (reg & 3));
                    #pragma unroll
                    for (int dt2 = 0; dt2 < 4; dt2++) o[dt2][reg] *= ar;
                }
                m = nm;
            }

            // ---- exp2 + row-sum ----
            float rsum = 0.f;
            #pragma unroll
            for (int reg = 0; reg < 16; reg++) {
                float e = __builtin_exp2f(stc[reg] - m);
                stc[reg] = e;
                rsum += e;
            }
            rsum += __shfl_xor(rsum, 32);
            lsum += rsum;

            // ---- pack P to f16 dwords ----
            int pk[8];
            #pragma unroll
            for (int oo = 0; oo < 4; oo++)
                #pragma unroll
                for (int c = 0; c < 2; c++) {
                    half2_t hp;
                    hp[0] = (_Float16)stc[4 * oo + 2 * c];
                    hp[1] = (_Float16)stc[4 * oo + 2 * c + 1];
                    pk[2 * oo + c] = __builtin_bit_cast(int, hp);
                }

            // ---- PV: 2 x 16-key steps, A-frag assembled in-register ----
            __builtin_amdgcn_s_setprio(1);
            #pragma unroll
            for (int ks = 0; ks < 2; ks++) {
                int base = ks * 4;
                int z0 = hi ? pk[base + 0] : pk[base + 2];
                int z1 = hi ? pk[base + 1] : pk[base + 3];
                int xz0 = __shfl_xor(z0, 32);
                int xz1 = __shfl_xor(z1, 32);
                int4_t pi;
                pi[0] = hi ? xz0 : pk[base + 0];
                pi[1] = hi ? xz1 : pk[base + 1];
                pi[2] = hi ? pk[base + 2] : xz0;
                pi[3] = hi ? pk[base + 3] : xz1;
                half8 pfrag = __builtin_bit_cast(half8, pi);
                #pragma unroll
                for (int dt2 = 0; dt2 < 4; dt2++) {
                    half8 vfr = *(const half8*)(bufV + (dt2 * 32 + l31) * (VROW_F16 * 2) + ks * 32 + hi * 16);
                    o[dt2] = __builtin_amdgcn_mfma_f32_32x32x16_f16(pfrag, vfr, o[dt2], 0, 0, 0);
                }
            }
            __builtin_amdgcn_s_setprio(0);
        }

        __builtin_amdgcn_sched_barrier(0);
        asm volatile("" ::: "memory");     // pin LDS reads above the barrier
        __builtin_amdgcn_s_barrier();      // all waves done reading buf[cur]
        __builtin_amdgcn_sched_barrier(0);
        if (kt + 2 < nt) STAGE_T(cur, kt + 2);
    }
    #undef STAGE_T

    float invl = 1.0f / lsum;
    #pragma unroll
    for (int reg = 0; reg < 16; reg++) {
        int qrow = 8 * (reg >> 2) + 4 * hi + (reg & 3);
        float ir = __shfl(invl, qrow);
        _Float16* orow = ctx + (size_t)(b * T_ + qW + qrow) * (H_ * HD_) + h * HD_ + l31;
        #pragma unroll
        for (int dt2 = 0; dt2 < 4; dt2++)
            orow[dt2 * 32] = (_Float16)(o[dt2][reg] * ir);
    }
}

// ---------------- launch ----------------
extern "C" void kernel_launch(void* const* d_in, const int* in_sizes, int n_in,
                              void* d_out, int out_size, void* d_ws, size_t ws_size,
                              hipStream_t stream) {
    const float* x   = (const float*)d_in[0];
    const float* Wq  = (const float*)d_in[1];
    const float* Wk  = (const float*)d_in[2];
    const float* Wv  = (const float*)d_in[3];
    const float* Wo  = (const float*)d_in[4];
    const float* qnw = (const float*)d_in[5];
    const float* knw = (const float*)d_in[6];
    float* out = (float*)d_out;

    char* ws = (char*)d_ws;
    size_t off = 0;
    auto alloc = [&](size_t bytes) {
        char* p = ws + off;
        off += (bytes + 255) & ~(size_t)255;
        return p;
    };
    _Float16* x_h  = (_Float16*)alloc((size_t)B_ * T_ * D_ * 2);        // reused as q_h
    _Float16* wq_h = (_Float16*)alloc((size_t)H_ * HD_ * D_ * 2);       // reused as kvimg (with wk_h)
    _Float16* wk_h = (_Float16*)alloc((size_t)G_ * HD_ * D_ * 2);
    _Float16* wv_h = (_Float16*)alloc((size_t)G_ * HD_ * D_ * 2);
    _Float16* wo_h = (_Float16*)alloc((size_t)D_ * H_ * HD_ * 2);
    float* q_f = (float*)alloc((size_t)B_ * T_ * H_ * HD_ * 4);
    float* k_f = (float*)alloc((size_t)B_ * T_ * G_ * HD_ * 4);
    float* v_f = (float*)alloc((size_t)B_ * T_ * G_ * HD_ * 4);
    _Float16* ctx_h = (_Float16*)alloc((size_t)B_ * T_ * H_ * HD_ * 2);
    float* cosT = (float*)alloc((size_t)T_ * 64 * 4);
    float* sinT = (float*)alloc((size_t)T_ * 64 * 4);

    // aliases (lifetimes disjoint):
    _Float16* q_h   = x_h;     // x_h dead after QKV GEMM
    _Float16* kvimg = wq_h;    // wq_h+wk_h dead after QKV GEMM; image = 512*20480 = 10.5 MB

    // fused vectorized conversions + rope tables
    cvt_all<<<2048, 256, 0, stream>>>(x, Wq, Wk, Wv, Wo, x_h, wq_h, wk_h, wv_h, wo_h);
    rope_tables_k<<<(T_ * 64) / 256, 256, 0, stream>>>(cosT, sinT);

    // fused Q+K+V projection: 128x128 tiles, counted-vmcnt pipeline
    gemm_tile<<<dim3(32, 24), 256, 0, stream>>>(x_h, wq_h, q_f, 16,
                                                wk_h, k_f, 4,
                                                wv_h, v_f, 4, D_);

    // fused Q+K norm+rope (Q -> f16 with log2e/128 scale; K in-place f32)
    rmsnorm_rope_qk<<<(B_ * T_ * (H_ + G_)) / 4, 256, 0, stream>>>(q_f, k_f, qnw, knw, cosT, sinT, q_h);

    // pack K/V into combined padded f16 tile images (32-key tiles)
    pack_kv<<<512, 256, 0, stream>>>(k_f, v_f, kvimg);

    // causal GQA attention -> ctx (f16)
    attn_mfma8<<<512, 256, 0, stream>>>(q_h, kvimg, ctx_h);

    // output projection: 128x128 tiles, counted-vmcnt pipeline
    gemm_tile<<<dim3(32, 16), 256, 0, stream>>>(ctx_h, wo_h, out, 16,
                                                nullptr, nullptr, 0,
                                                nullptr, nullptr, 0, H_ * HD_);
}

// Round 14
// 222.401 us; speedup vs baseline: 1.2599x; 1.2599x over previous
//
#include <hip/hip_runtime.h>
#include <hip/hip_bf16.h>

// Problem constants (match reference)
#define B_ 2
#define T_ 2048
#define D_ 2048
#define H_ 16
#define G_ 4
#define HD_ 128
#define GS_ (H_/G_)

typedef _Float16 half8 __attribute__((ext_vector_type(8)));
typedef _Float16 half2_t __attribute__((ext_vector_type(2)));
typedef float f32x4 __attribute__((ext_vector_type(4)));
typedef float f32x16 __attribute__((ext_vector_type(16)));
typedef int int4_t __attribute__((ext_vector_type(4)));

// Combined KV tile image: per (b,g,tile64): [K: 64 rows x 136 f16 (128 data + 8 pad)]
// then [V^T: 128 rows x 72 f16 (64 data + 8 pad)], padded to 36864 B so each of the
// 4 waves stages exactly 9 x 1024B groups (uniform vmcnt counting).
#define KV_TILE_BYTES 36864
#define KROW_F16 136
#define VROW_F16 72
#define VBASE_F16 8704   // 17408 bytes / 2

// ---------------- fused vectorized fp32 -> fp16 conversion (x, Wq, Wk, Wv, Wo) ----------------
#define C0_ 1048576   // x:  8388608/8
#define C1_ 1572864   // +Wq 4194304/8
#define C2_ 1703936   // +Wk 1048576/8
#define C3_ 1835008   // +Wv 1048576/8
#define C4_ 2359296   // +Wo 4194304/8
__global__ void cvt_all(const float* __restrict__ sx, const float* __restrict__ sq,
                        const float* __restrict__ sk, const float* __restrict__ sv,
                        const float* __restrict__ so,
                        _Float16* __restrict__ dx, _Float16* __restrict__ dq,
                        _Float16* __restrict__ dk, _Float16* __restrict__ dv,
                        _Float16* __restrict__ dw) {
    int g = blockIdx.x * blockDim.x + threadIdx.x;
    int stride = blockDim.x * gridDim.x;
    for (; g < C4_; g += stride) {
        const float* src; _Float16* dst; int local;
        if (g < C0_)      { src = sx; dst = dx; local = g; }
        else if (g < C1_) { src = sq; dst = dq; local = g - C0_; }
        else if (g < C2_) { src = sk; dst = dk; local = g - C1_; }
        else if (g < C3_) { src = sv; dst = dv; local = g - C2_; }
        else              { src = so; dst = dw; local = g - C3_; }
        f32x4 a = *((const f32x4*)src + local * 2);
        f32x4 b = *((const f32x4*)src + local * 2 + 1);
        half8 hv;
        hv[0] = (_Float16)a[0]; hv[1] = (_Float16)a[1];
        hv[2] = (_Float16)a[2]; hv[3] = (_Float16)a[3];
        hv[4] = (_Float16)b[0]; hv[5] = (_Float16)b[1];
        hv[6] = (_Float16)b[2]; hv[7] = (_Float16)b[3];
        *((half8*)dst + local) = hv;
    }
}

// ---------------- RoPE tables: cos/sin (T_, 64) ----------------
__global__ void rope_tables_k(float* __restrict__ cosT, float* __restrict__ sinT) {
    int i = blockIdx.x * blockDim.x + threadIdx.x; // T_*64 threads
    int t = i >> 6, l = i & 63;
    float inv_freq = powf(10000.0f, -((float)(2 * l)) / 128.0f);
    float a = (float)t * inv_freq;
    cosT[i] = cosf(a);
    sinT[i] = sinf(a);
}

// ---------------- Tiled TN GEMM, 128x128 tile, 2-deep counted-vmcnt pipeline ----------------
__global__ void __launch_bounds__(256) gemm_tile(const _Float16* __restrict__ A,
                                                 const _Float16* __restrict__ B0,
                                                 float* __restrict__ C0, int n0t,
                                                 const _Float16* __restrict__ B1,
                                                 float* __restrict__ C1, int n1t,
                                                 const _Float16* __restrict__ B2,
                                                 float* __restrict__ C2, int n2t,
                                                 int Kd) {
    __shared__ _Float16 sA[2][128 * 32];
    __shared__ _Float16 sB[2][128 * 32];

    int tid = threadIdx.x;
    int w = tid >> 6, lane = tid & 63;
    int l15 = lane & 15, g4 = lane >> 4;
    int wm = w >> 1, wn = w & 1;

    int y = blockIdx.y;
    const _Float16* Bsel;
    float* Csel;
    int ldc, cb;
    if (y < n0t)            { Bsel = B0; Csel = C0; ldc = n0t * 128; cb = y; }
    else if (y < n0t + n1t) { Bsel = B1; Csel = C1; ldc = n1t * 128; cb = y - n0t; }
    else                    { Bsel = B2; Csel = C2; ldc = n2t * 128; cb = y - n0t - n1t; }

    const _Float16* Ab = A + (size_t)(blockIdx.x * 128) * Kd;
    const _Float16* Bb = Bsel + (size_t)(cb * 128) * Kd;

    int s0 = w * 128 + lane;
    int s1 = s0 + 64;
    size_t ga0 = (size_t)(s0 >> 2) * Kd + (s0 & 3) * 8;
    size_t ga1 = (size_t)(s1 >> 2) * Kd + (s1 & 3) * 8;

    #define STAGE(BUF, K0)                                                                     \
        do {                                                                                   \
            _Float16* a0_ = &sA[BUF][0] + (size_t)(w * 2) * 512;                               \
            _Float16* a1_ = &sA[BUF][0] + (size_t)(w * 2 + 1) * 512;                           \
            _Float16* b0_ = &sB[BUF][0] + (size_t)(w * 2) * 512;                               \
            _Float16* b1_ = &sB[BUF][0] + (size_t)(w * 2 + 1) * 512;                           \
            __builtin_amdgcn_global_load_lds(                                                  \
                (const __attribute__((address_space(1))) unsigned int*)(Ab + ga0 + (K0)),      \
                (__attribute__((address_space(3))) unsigned int*)a0_, 16, 0, 0);               \
            __builtin_amdgcn_global_load_lds(                                                  \
                (const __attribute__((address_space(1))) unsigned int*)(Ab + ga1 + (K0)),      \
                (__attribute__((address_space(3))) unsigned int*)a1_, 16, 0, 0);               \
            __builtin_amdgcn_global_load_lds(                                                  \
                (const __attribute__((address_space(1))) unsigned int*)(Bb + ga0 + (K0)),      \
                (__attribute__((address_space(3))) unsigned int*)b0_, 16, 0, 0);               \
            __builtin_amdgcn_global_load_lds(                                                  \
                (const __attribute__((address_space(1))) unsigned int*)(Bb + ga1 + (K0)),      \
                (__attribute__((address_space(3))) unsigned int*)b1_, 16, 0, 0);               \
        } while (0)

    f32x4 acc[4][4];
    #pragma unroll
    for (int i = 0; i < 4; i++)
        #pragma unroll
        for (int j = 0; j < 4; j++) acc[i][j] = (f32x4){0.f, 0.f, 0.f, 0.f};

    int nIt = Kd >> 5;
    STAGE(0, 0);
    if (nIt > 1) STAGE(1, 32);

    for (int it = 0; it < nIt; ++it) {
        int cur = it & 1;
        if (it + 1 < nIt) asm volatile("s_waitcnt vmcnt(4)" ::: "memory");
        else              asm volatile("s_waitcnt vmcnt(0)" ::: "memory");
        __builtin_amdgcn_sched_barrier(0);
        __builtin_amdgcn_s_barrier();          // all waves' tile-it loads landed
        __builtin_amdgcn_sched_barrier(0);

        half8 af[4], bf[4];
        #pragma unroll
        for (int mi = 0; mi < 4; mi++)
            af[mi] = *(const half8*)&sA[cur][(wm * 64 + mi * 16 + l15) * 32 + g4 * 8];
        #pragma unroll
        for (int ni = 0; ni < 4; ni++)
            bf[ni] = *(const half8*)&sB[cur][(wn * 64 + ni * 16 + l15) * 32 + g4 * 8];

        #pragma unroll
        for (int mi = 0; mi < 4; mi++)
            #pragma unroll
            for (int ni = 0; ni < 4; ni++)
                acc[mi][ni] = __builtin_amdgcn_mfma_f32_16x16x32_f16(af[mi], bf[ni], acc[mi][ni], 0, 0, 0);

        __builtin_amdgcn_sched_barrier(0);
        asm volatile("" ::: "memory");         // pin LDS reads above the barrier
        __builtin_amdgcn_s_barrier();          // all waves done reading buf[cur]
        __builtin_amdgcn_sched_barrier(0);
        if (it + 2 < nIt) STAGE(cur, (size_t)(it + 2) * 32);
    }
    #undef STAGE

    int rbase = blockIdx.x * 128 + wm * 64 + g4 * 4;
    int cbase = cb * 128 + wn * 64 + l15;
    #pragma unroll
    for (int mi = 0; mi < 4; mi++)
        #pragma unroll
        for (int r = 0; r < 4; r++) {
            float* crow = Csel + (size_t)(rbase + mi * 16 + r) * ldc + cbase;
            #pragma unroll
            for (int ni = 0; ni < 4; ni++) crow[ni * 16] = acc[mi][ni][r];
        }
}

// ---------------- fused RMSNorm + RoPE (Q and K in one dispatch) ----------------
// Q scale folds BOTH the attention score scale (1/128) and log2(e) so attention
// scores come out in the log2 domain (softmax uses exp2 directly).
__global__ void rmsnorm_rope_qk(float* __restrict__ Qf, float* __restrict__ Kf,
                                const float* __restrict__ qw, const float* __restrict__ kw,
                                const float* __restrict__ cosT, const float* __restrict__ sinT,
                                _Float16* __restrict__ qH) {
    int gw = (int)((blockIdx.x * (size_t)blockDim.x + threadIdx.x) >> 6);
    int lane = threadIdx.x & 63;
    bool isQ = gw < (B_ * T_ * H_);
    int row_i = isQ ? gw : gw - (B_ * T_ * H_);
    int heads = isQ ? H_ : G_;
    const float* wv = isQ ? qw : kw;
    float* row = (isQ ? Qf : Kf) + (size_t)row_i * HD_;
    int t = (row_i / heads) % T_;
    float x0 = row[lane];
    float x1 = row[lane + 64];
    float ss = x0 * x0 + x1 * x1;
    #pragma unroll
    for (int off = 1; off < 64; off <<= 1) ss += __shfl_xor(ss, off);
    float inv = rsqrtf(ss * (1.0f / 128.0f) + 1e-6f);
    float n0 = x0 * inv * wv[lane];
    float n1 = x1 * inv * wv[lane + 64];
    float c = cosT[t * 64 + lane];
    float s = sinT[t * 64 + lane];
    float r0 = n0 * c - n1 * s;
    float r1 = n1 * c + n0 * s;
    if (isQ) {
        const float QSCL = 1.44269504089f / 128.0f;   // log2(e) * (1/HD)
        qH[(size_t)row_i * HD_ + lane]      = (_Float16)(r0 * QSCL);
        qH[(size_t)row_i * HD_ + lane + 64] = (_Float16)(r1 * QSCL);
    } else {
        row[lane]      = r0;
        row[lane + 64] = r1;
    }
}

// ---------------- pack K+V into combined padded f16 tile image (64-key tiles) ----------------
__global__ void __launch_bounds__(256) pack_kv(const float* __restrict__ kf,
                                               const float* __restrict__ vf,
                                               _Float16* __restrict__ img) {
    int bid = blockIdx.x;
    int tile = bid & 31, g = (bid >> 5) & 3, b = bid >> 7;
    int tid = threadIdx.x;
    _Float16* out = img + (size_t)bid * (KV_TILE_BYTES / 2);

    // K part: 64 rows x 17 granules (granule 16 = pad)
    #pragma unroll
    for (int it = 0; it < 5; it++) {
        int gi = tid + 256 * it;
        if (gi < 64 * 17) {
            int key = gi / 17, gr = gi % 17;
            half8 hv = (half8){0, 0, 0, 0, 0, 0, 0, 0};
            if (gr < 16) {
                const float* src = kf + ((size_t)((b * T_ + tile * 64 + key) * G_ + g)) * HD_ + gr * 8;
                #pragma unroll
                for (int j = 0; j < 8; j++) hv[j] = (_Float16)src[j];
            }
            *(half8*)(out + (size_t)gi * 8) = hv;
        }
    }
    // V^T part: 128 rows (d) x 9 granules (granule 8 = pad); strided gather transpose
    #pragma unroll
    for (int it = 0; it < 5; it++) {
        int vi = tid + 256 * it;
        if (vi < 128 * 9) {
            int d = vi / 9, gr = vi % 9;
            half8 hv = (half8){0, 0, 0, 0, 0, 0, 0, 0};
            if (gr < 8) {
                const float* src = vf + ((size_t)((b * T_ + tile * 64 + gr * 8) * G_ + g)) * HD_ + d;
                #pragma unroll
                for (int j = 0; j < 8; j++) hv[j] = (_Float16)src[(size_t)j * (G_ * HD_)];
            }
            *(half8*)(out + VBASE_F16 + (size_t)vi * 8) = hv;
        }
    }
}

// ---------------- causal GQA flash attention v9 ----------------
// R9/R10-verified 64-key structure + exp2 log2-domain softmax (verified R11/R13)
// + diagonal-tile-only masking + balanced-tree reductions. Monolithic pack->PV
// (the measured-good v5 form). All cross-lane via __shfl_xor (no permlane).
__global__ void __launch_bounds__(256, 2) attn_mfma9(const _Float16* __restrict__ qh,
                                                     const _Float16* __restrict__ kvimg,
                                                     _Float16* __restrict__ ctx) {
    int id = blockIdx.x;
    int hlf = id >> 8, rr0 = id & 255;
    int qb = hlf ? (15 - (rr0 & 15)) : (rr0 & 15);
    int hb = (rr0 >> 4) | (hlf << 4);
    int h = hb & 15, b = hb >> 4;
    int g = h >> 2;

    int tid = threadIdx.x;
    int w = tid >> 6, lane = tid & 63;
    int l31 = lane & 31, hi = lane >> 5;

    __shared__ __align__(16) char sKV[2][KV_TILE_BYTES];

    int qW = qb * 128 + w * 32;
    int qme = qW + l31;

    half8 qfrag[8];
    {
        const _Float16* qrow = qh + ((size_t)(b * T_ + qme)) * (H_ * HD_) + h * HD_ + hi * 8;
        #pragma unroll
        for (int ks = 0; ks < 8; ks++) qfrag[ks] = *(const half8*)(qrow + ks * 16);
    }

    f32x16 o[4];
    #pragma unroll
    for (int dt2 = 0; dt2 < 4; dt2++)
        #pragma unroll
        for (int r = 0; r < 16; r++) o[dt2][r] = 0.f;
    float m = -INFINITY, lsum = 0.f;

    const char* ibase = (const char*)kvimg + (size_t)((b * 4 + g) * 32) * KV_TILE_BYTES;

    // 36 groups of 1024B per tile; wave w takes groups w, w+4, ..., w+32 (9 each)
    #define STAGE_T(BUF, KT)                                                                       \
        do {                                                                                       \
            const char* src_ = ibase + (size_t)(KT) * KV_TILE_BYTES;                               \
            char* dst_ = &sKV[BUF][0];                                                             \
            _Pragma("unroll")                                                                      \
            for (int i_ = 0; i_ < 9; i_++) {                                                       \
                int c_ = w + 4 * i_;                                                               \
                __builtin_amdgcn_global_load_lds(                                                  \
                    (const __attribute__((address_space(1))) unsigned int*)(src_ + c_ * 1024 + lane * 16), \
                    (__attribute__((address_space(3))) unsigned int*)(dst_ + c_ * 1024 + lane * 16), 16, 0, 0); \
            }                                                                                      \
        } while (0)

    int nt = 2 * qb + 2;
    int ktmax_w = (qW + 31) >> 6;

    STAGE_T(0, 0);
    STAGE_T(1, 1);      // nt >= 2 always

    for (int kt = 0; kt < nt; kt++) {
        int cur = kt & 1;
        if (kt + 1 < nt) asm volatile("s_waitcnt vmcnt(9)" ::: "memory");
        else             asm volatile("s_waitcnt vmcnt(0)" ::: "memory");
        __builtin_amdgcn_sched_barrier(0);
        __builtin_amdgcn_s_barrier();      // all waves' tile-kt loads landed
        __builtin_amdgcn_sched_barrier(0);

        if (kt <= ktmax_w) {
            const char* bufK = &sKV[cur][0];
            const char* bufV = &sKV[cur][0] + VBASE_F16 * 2;

            // ---- swapped QK^T (scores in log2 domain via Q scale) ----
            f32x16 stc[2];
            #pragma unroll
            for (int kt2 = 0; kt2 < 2; kt2++)
                #pragma unroll
                for (int r = 0; r < 16; r++) stc[kt2][r] = 0.f;

            __builtin_amdgcn_s_setprio(1);
            #pragma unroll
            for (int ks = 0; ks < 8; ks++) {
                #pragma unroll
                for (int kt2 = 0; kt2 < 2; kt2++) {
                    half8 kfr = *(const half8*)(bufK + (kt2 * 32 + l31) * (KROW_F16 * 2) + ks * 32 + hi * 16);
                    stc[kt2] = __builtin_amdgcn_mfma_f32_32x32x16_f16(kfr, qfrag[ks], stc[kt2], 0, 0, 0);
                }
            }
            __builtin_amdgcn_s_setprio(0);

            // ---- causal mask: only the diagonal tile is partial (wave-uniform) ----
            if (kt == ktmax_w) {
                #pragma unroll
                for (int kt2 = 0; kt2 < 2; kt2++)
                    #pragma unroll
                    for (int reg = 0; reg < 16; reg++) {
                        int key = kt * 64 + kt2 * 32 + 8 * (reg >> 2) + 4 * hi + (reg & 3);
                        float v = stc[kt2][reg];
                        stc[kt2][reg] = (key <= qme) ? v : -INFINITY;
                    }
            }

            // ---- pmax: balanced tree ----
            float pm[8];
            #pragma unroll
            for (int i = 0; i < 8; i++) {
                const f32x16& sv = stc[i >> 2];
                int base = (i & 3) * 4;
                float a = fmaxf(sv[base + 0], sv[base + 1]);
                float bq = fmaxf(sv[base + 2], sv[base + 3]);
                pm[i] = fmaxf(a, bq);
            }
            float pmax = fmaxf(fmaxf(fmaxf(pm[0], pm[1]), fmaxf(pm[2], pm[3])),
                               fmaxf(fmaxf(pm[4], pm[5]), fmaxf(pm[6], pm[7])));
            pmax = fmaxf(pmax, __shfl_xor(pmax, 32));

            // ---- defer-max rescale (thr 11.5 in log2 domain ~ e^8) ----
            if (__any(!(pmax - m <= 11.5f))) {
                float nm = fmaxf(m, pmax);
                float alpha = __builtin_exp2f(m - nm);   // first tile: 2^-inf = 0
                lsum *= alpha;
                #pragma unroll
                for (int reg = 0; reg < 16; reg++) {
                    float ar = __shfl(alpha, 8 * (reg >> 2) + 4 * hi + (reg & 3));
                    #pragma unroll
                    for (int dt2 = 0; dt2 < 4; dt2++) o[dt2][reg] *= ar;
                }
                m = nm;
            }

            // ---- exp2 + row-sum (balanced tree) ----
            float rs[8];
            #pragma unroll
            for (int i = 0; i < 8; i++) {
                f32x16& sv = stc[i >> 2];
                int base = (i & 3) * 4;
                float e0 = __builtin_exp2f(sv[base + 0] - m);
                float e1 = __builtin_exp2f(sv[base + 1] - m);
                float e2 = __builtin_exp2f(sv[base + 2] - m);
                float e3 = __builtin_exp2f(sv[base + 3] - m);
                sv[base + 0] = e0; sv[base + 1] = e1; sv[base + 2] = e2; sv[base + 3] = e3;
                rs[i] = (e0 + e1) + (e2 + e3);
            }
            float rsum = ((rs[0] + rs[1]) + (rs[2] + rs[3])) + ((rs[4] + rs[5]) + (rs[6] + rs[7]));
            rsum += __shfl_xor(rsum, 32);
            lsum += rsum;

            // ---- pack P to f16 dwords (monolithic, v5 form) ----
            int pk[16];
            #pragma unroll
            for (int kt2 = 0; kt2 < 2; kt2++)
                #pragma unroll
                for (int oo = 0; oo < 4; oo++)
                    #pragma unroll
                    for (int c = 0; c < 2; c++) {
                        half2_t hp;
                        hp[0] = (_Float16)stc[kt2][4 * oo + 2 * c];
                        hp[1] = (_Float16)stc[kt2][4 * oo + 2 * c + 1];
                        pk[kt2 * 8 + 2 * oo + c] = __builtin_bit_cast(int, hp);
                    }

            // ---- PV: 4 x 16-key steps, A-frag assembled in-register ----
            __builtin_amdgcn_s_setprio(1);
            #pragma unroll
            for (int ks = 0; ks < 4; ks++) {
                int base = (ks >> 1) * 8 + (ks & 1) * 4;
                int z0 = hi ? pk[base + 0] : pk[base + 2];
                int z1 = hi ? pk[base + 1] : pk[base + 3];
                int xz0 = __shfl_xor(z0, 32);
                int xz1 = __shfl_xor(z1, 32);
                int4_t pi;
                pi[0] = hi ? xz0 : pk[base + 0];
                pi[1] = hi ? xz1 : pk[base + 1];
                pi[2] = hi ? pk[base + 2] : xz0;
                pi[3] = hi ? pk[base + 3] : xz1;
                half8 pfrag = __builtin_bit_cast(half8, pi);
                #pragma unroll
                for (int dt2 = 0; dt2 < 4; dt2++) {
                    half8 vfr = *(const half8*)(bufV + (dt2 * 32 + l31) * (VROW_F16 * 2) + ks * 32 + hi * 16);
                    o[dt2] = __builtin_amdgcn_mfma_f32_32x32x16_f16(pfrag, vfr, o[dt2], 0, 0, 0);
                }
            }
            __builtin_amdgcn_s_setprio(0);
        }

        __builtin_amdgcn_sched_barrier(0);
        asm volatile("" ::: "memory");     // pin LDS reads above the barrier
        __builtin_amdgcn_s_barrier();      // all waves done reading buf[cur]
        __builtin_amdgcn_sched_barrier(0);
        if (kt + 2 < nt) STAGE_T(cur, kt + 2);
    }
    #undef STAGE_T

    float invl = 1.0f / lsum;
    #pragma unroll
    for (int reg = 0; reg < 16; reg++) {
        int qrow = 8 * (reg >> 2) + 4 * hi + (reg & 3);
        float ir = __shfl(invl, qrow);
        _Float16* orow = ctx + (size_t)(b * T_ + qW + qrow) * (H_ * HD_) + h * HD_ + l31;
        #pragma unroll
        for (int dt2 = 0; dt2 < 4; dt2++)
            orow[dt2 * 32] = (_Float16)(o[dt2][reg] * ir);
    }
}

// ---------------- launch ----------------
extern "C" void kernel_launch(void* const* d_in, const int* in_sizes, int n_in,
                              void* d_out, int out_size, void* d_ws, size_t ws_size,
                              hipStream_t stream) {
    const float* x   = (const float*)d_in[0];
    const float* Wq  = (const float*)d_in[1];
    const float* Wk  = (const float*)d_in[2];
    const float* Wv  = (const float*)d_in[3];
    const float* Wo  = (const float*)d_in[4];
    const float* qnw = (const float*)d_in[5];
    const float* knw = (const float*)d_in[6];
    float* out = (float*)d_out;

    char* ws = (char*)d_ws;
    size_t off = 0;
    auto alloc = [&](size_t bytes) {
        char* p = ws + off;
        off += (bytes + 255) & ~(size_t)255;
        return p;
    };
    _Float16* x_h  = (_Float16*)alloc((size_t)B_ * T_ * D_ * 2);        // reused as q_h
    _Float16* wq_h = (_Float16*)alloc((size_t)H_ * HD_ * D_ * 2);       // reused as kvimg (with wk_h)
    _Float16* wk_h = (_Float16*)alloc((size_t)G_ * HD_ * D_ * 2);
    _Float16* wv_h = (_Float16*)alloc((size_t)G_ * HD_ * D_ * 2);
    _Float16* wo_h = (_Float16*)alloc((size_t)D_ * H_ * HD_ * 2);
    float* q_f = (float*)alloc((size_t)B_ * T_ * H_ * HD_ * 4);
    float* k_f = (float*)alloc((size_t)B_ * T_ * G_ * HD_ * 4);
    float* v_f = (float*)alloc((size_t)B_ * T_ * G_ * HD_ * 4);
    _Float16* ctx_h = (_Float16*)alloc((size_t)B_ * T_ * H_ * HD_ * 2);
    float* cosT = (float*)alloc((size_t)T_ * 64 * 4);
    float* sinT = (float*)alloc((size_t)T_ * 64 * 4);

    // aliases (lifetimes disjoint):
    _Float16* q_h   = x_h;     // x_h dead after QKV GEMM
    _Float16* kvimg = wq_h;    // wq_h+wk_h dead after QKV GEMM; image = 256*36864 = 9.4 MB

    // fused vectorized conversions + rope tables
    cvt_all<<<2048, 256, 0, stream>>>(x, Wq, Wk, Wv, Wo, x_h, wq_h, wk_h, wv_h, wo_h);
    rope_tables_k<<<(T_ * 64) / 256, 256, 0, stream>>>(cosT, sinT);

    // fused Q+K+V projection: 128x128 tiles, counted-vmcnt pipeline
    gemm_tile<<<dim3(32, 24), 256, 0, stream>>>(x_h, wq_h, q_f, 16,
                                                wk_h, k_f, 4,
                                                wv_h, v_f, 4, D_);

    // fused Q+K norm+rope (Q -> f16 with log2e/128 scale; K in-place f32)
    rmsnorm_rope_qk<<<(B_ * T_ * (H_ + G_)) / 4, 256, 0, stream>>>(q_f, k_f, qnw, knw, cosT, sinT, q_h);

    // pack K/V into combined padded f16 tile images (64-key tiles)
    pack_kv<<<256, 256, 0, stream>>>(k_f, v_f, kvimg);

    // causal GQA attention -> ctx (f16)
    attn_mfma9<<<512, 256, 0, stream>>>(q_h, kvimg, ctx_h);

    // output projection: 128x128 tiles, counted-vmcnt pipeline
    gemm_tile<<<dim3(32, 16), 256, 0, stream>>>(ctx_h, wo_h, out, 16,
                                                nullptr, nullptr, 0,
                                                nullptr, nullptr, 0, H_ * HD_);
}

// Round 15
// 219.589 us; speedup vs baseline: 1.2760x; 1.0128x over previous
//
#include <hip/hip_runtime.h>
#include <hip/hip_bf16.h>

// Problem constants (match reference)
#define B_ 2
#define T_ 2048
#define D_ 2048
#define H_ 16
#define G_ 4
#define HD_ 128
#define GS_ (H_/G_)

typedef _Float16 half8 __attribute__((ext_vector_type(8)));
typedef _Float16 half2_t __attribute__((ext_vector_type(2)));
typedef float f32x4 __attribute__((ext_vector_type(4)));
typedef float f32x16 __attribute__((ext_vector_type(16)));
typedef int int4_t __attribute__((ext_vector_type(4)));

// Combined KV tile image: per (b,g,tile64): [K: 64 rows x 136 f16 (128 data + 8 pad)]
// then [V^T: 128 rows x 72 f16 (64 data + 8 pad)], padded to 36864 B so each of the
// 4 waves stages exactly 9 x 1024B groups (uniform vmcnt counting).
#define KV_TILE_BYTES 36864
#define KROW_F16 136
#define VROW_F16 72
#define VBASE_F16 8704   // 17408 bytes / 2

// ---------------- fused vectorized fp32 -> fp16 conversion (x, Wq, Wk, Wv, Wo) ----------------
#define C0_ 1048576   // x:  8388608/8
#define C1_ 1572864   // +Wq 4194304/8
#define C2_ 1703936   // +Wk 1048576/8
#define C3_ 1835008   // +Wv 1048576/8
#define C4_ 2359296   // +Wo 4194304/8
__global__ void cvt_all(const float* __restrict__ sx, const float* __restrict__ sq,
                        const float* __restrict__ sk, const float* __restrict__ sv,
                        const float* __restrict__ so,
                        _Float16* __restrict__ dx, _Float16* __restrict__ dq,
                        _Float16* __restrict__ dk, _Float16* __restrict__ dv,
                        _Float16* __restrict__ dw) {
    int g = blockIdx.x * blockDim.x + threadIdx.x;
    int stride = blockDim.x * gridDim.x;
    for (; g < C4_; g += stride) {
        const float* src; _Float16* dst; int local;
        if (g < C0_)      { src = sx; dst = dx; local = g; }
        else if (g < C1_) { src = sq; dst = dq; local = g - C0_; }
        else if (g < C2_) { src = sk; dst = dk; local = g - C1_; }
        else if (g < C3_) { src = sv; dst = dv; local = g - C2_; }
        else              { src = so; dst = dw; local = g - C3_; }
        f32x4 a = *((const f32x4*)src + local * 2);
        f32x4 b = *((const f32x4*)src + local * 2 + 1);
        half8 hv;
        hv[0] = (_Float16)a[0]; hv[1] = (_Float16)a[1];
        hv[2] = (_Float16)a[2]; hv[3] = (_Float16)a[3];
        hv[4] = (_Float16)b[0]; hv[5] = (_Float16)b[1];
        hv[6] = (_Float16)b[2]; hv[7] = (_Float16)b[3];
        *((half8*)dst + local) = hv;
    }
}

// ---------------- RoPE tables: cos/sin (T_, 64) ----------------
__global__ void rope_tables_k(float* __restrict__ cosT, float* __restrict__ sinT) {
    int i = blockIdx.x * blockDim.x + threadIdx.x; // T_*64 threads
    int t = i >> 6, l = i & 63;
    float inv_freq = powf(10000.0f, -((float)(2 * l)) / 128.0f);
    float a = (float)t * inv_freq;
    cosT[i] = cosf(a);
    sinT[i] = sinf(a);
}

// ---------------- Tiled TN GEMM, 128x128 tile, 3-deep counted-vmcnt pipeline ----------------
// Double lookahead: prologue stages tiles 0,1,2; steady-state wait vmcnt(8)
// (this tile's 4 loads done; 8 from the next two tiles stay in flight).
__global__ void __launch_bounds__(256) gemm_tile(const _Float16* __restrict__ A,
                                                 const _Float16* __restrict__ B0,
                                                 float* __restrict__ C0, int n0t,
                                                 const _Float16* __restrict__ B1,
                                                 float* __restrict__ C1, int n1t,
                                                 const _Float16* __restrict__ B2,
                                                 float* __restrict__ C2, int n2t,
                                                 int Kd) {
    __shared__ _Float16 sA[3][128 * 32];
    __shared__ _Float16 sB[3][128 * 32];

    int tid = threadIdx.x;
    int w = tid >> 6, lane = tid & 63;
    int l15 = lane & 15, g4 = lane >> 4;
    int wm = w >> 1, wn = w & 1;

    int y = blockIdx.y;
    const _Float16* Bsel;
    float* Csel;
    int ldc, cb;
    if (y < n0t)            { Bsel = B0; Csel = C0; ldc = n0t * 128; cb = y; }
    else if (y < n0t + n1t) { Bsel = B1; Csel = C1; ldc = n1t * 128; cb = y - n0t; }
    else                    { Bsel = B2; Csel = C2; ldc = n2t * 128; cb = y - n0t - n1t; }

    const _Float16* Ab = A + (size_t)(blockIdx.x * 128) * Kd;
    const _Float16* Bb = Bsel + (size_t)(cb * 128) * Kd;

    int s0 = w * 128 + lane;
    int s1 = s0 + 64;
    size_t ga0 = (size_t)(s0 >> 2) * Kd + (s0 & 3) * 8;
    size_t ga1 = (size_t)(s1 >> 2) * Kd + (s1 & 3) * 8;

    #define STAGE(BUF, K0)                                                                     \
        do {                                                                                   \
            _Float16* a0_ = &sA[BUF][0] + (size_t)(w * 2) * 512;                               \
            _Float16* a1_ = &sA[BUF][0] + (size_t)(w * 2 + 1) * 512;                           \
            _Float16* b0_ = &sB[BUF][0] + (size_t)(w * 2) * 512;                               \
            _Float16* b1_ = &sB[BUF][0] + (size_t)(w * 2 + 1) * 512;                           \
            __builtin_amdgcn_global_load_lds(                                                  \
                (const __attribute__((address_space(1))) unsigned int*)(Ab + ga0 + (K0)),      \
                (__attribute__((address_space(3))) unsigned int*)a0_, 16, 0, 0);               \
            __builtin_amdgcn_global_load_lds(                                                  \
                (const __attribute__((address_space(1))) unsigned int*)(Ab + ga1 + (K0)),      \
                (__attribute__((address_space(3))) unsigned int*)a1_, 16, 0, 0);               \
            __builtin_amdgcn_global_load_lds(                                                  \
                (const __attribute__((address_space(1))) unsigned int*)(Bb + ga0 + (K0)),      \
                (__attribute__((address_space(3))) unsigned int*)b0_, 16, 0, 0);               \
            __builtin_amdgcn_global_load_lds(                                                  \
                (const __attribute__((address_space(1))) unsigned int*)(Bb + ga1 + (K0)),      \
                (__attribute__((address_space(3))) unsigned int*)b1_, 16, 0, 0);               \
        } while (0)

    f32x4 acc[4][4];
    #pragma unroll
    for (int i = 0; i < 4; i++)
        #pragma unroll
        for (int j = 0; j < 4; j++) acc[i][j] = (f32x4){0.f, 0.f, 0.f, 0.f};

    int nIt = Kd >> 5;
    STAGE(0, 0);
    if (nIt > 1) STAGE(1, 32);
    if (nIt > 2) STAGE(2, 64);

    int cur = 0;
    for (int it = 0; it < nIt; ++it) {
        if (it + 2 < nIt)      asm volatile("s_waitcnt vmcnt(8)" ::: "memory");
        else if (it + 1 < nIt) asm volatile("s_waitcnt vmcnt(4)" ::: "memory");
        else                   asm volatile("s_waitcnt vmcnt(0)" ::: "memory");
        __builtin_amdgcn_sched_barrier(0);
        __builtin_amdgcn_s_barrier();          // all waves' tile-it loads landed
        __builtin_amdgcn_sched_barrier(0);

        half8 af[4], bf[4];
        #pragma unroll
        for (int mi = 0; mi < 4; mi++)
            af[mi] = *(const half8*)&sA[cur][(wm * 64 + mi * 16 + l15) * 32 + g4 * 8];
        #pragma unroll
        for (int ni = 0; ni < 4; ni++)
            bf[ni] = *(const half8*)&sB[cur][(wn * 64 + ni * 16 + l15) * 32 + g4 * 8];

        #pragma unroll
        for (int mi = 0; mi < 4; mi++)
            #pragma unroll
            for (int ni = 0; ni < 4; ni++)
                acc[mi][ni] = __builtin_amdgcn_mfma_f32_16x16x32_f16(af[mi], bf[ni], acc[mi][ni], 0, 0, 0);

        __builtin_amdgcn_sched_barrier(0);
        asm volatile("" ::: "memory");         // pin LDS reads above the barrier
        __builtin_amdgcn_s_barrier();          // all waves done reading buf[cur]
        __builtin_amdgcn_sched_barrier(0);
        if (it + 3 < nIt) STAGE(cur, (size_t)(it + 3) * 32);
        cur = (cur == 2) ? 0 : cur + 1;
    }
    #undef STAGE

    int rbase = blockIdx.x * 128 + wm * 64 + g4 * 4;
    int cbase = cb * 128 + wn * 64 + l15;
    #pragma unroll
    for (int mi = 0; mi < 4; mi++)
        #pragma unroll
        for (int r = 0; r < 4; r++) {
            float* crow = Csel + (size_t)(rbase + mi * 16 + r) * ldc + cbase;
            #pragma unroll
            for (int ni = 0; ni < 4; ni++) crow[ni * 16] = acc[mi][ni][r];
        }
}

// ---------------- fused RMSNorm + RoPE (Q and K in one dispatch) ----------------
// Waves 0..65535: Q rows (B*T*H; write f16 q_h with 1/128 scale).
// Waves 65536..81919: K rows (B*T*G; f32 in-place).
__global__ void rmsnorm_rope_qk(float* __restrict__ Qf, float* __restrict__ Kf,
                                const float* __restrict__ qw, const float* __restrict__ kw,
                                const float* __restrict__ cosT, const float* __restrict__ sinT,
                                _Float16* __restrict__ qH) {
    int gw = (int)((blockIdx.x * (size_t)blockDim.x + threadIdx.x) >> 6);
    int lane = threadIdx.x & 63;
    bool isQ = gw < (B_ * T_ * H_);
    int row_i = isQ ? gw : gw - (B_ * T_ * H_);
    int heads = isQ ? H_ : G_;
    const float* wv = isQ ? qw : kw;
    float* row = (isQ ? Qf : Kf) + (size_t)row_i * HD_;
    int t = (row_i / heads) % T_;
    float x0 = row[lane];
    float x1 = row[lane + 64];
    float ss = x0 * x0 + x1 * x1;
    #pragma unroll
    for (int off = 1; off < 64; off <<= 1) ss += __shfl_xor(ss, off);
    float inv = rsqrtf(ss * (1.0f / 128.0f) + 1e-6f);
    float n0 = x0 * inv * wv[lane];
    float n1 = x1 * inv * wv[lane + 64];
    float c = cosT[t * 64 + lane];
    float s = sinT[t * 64 + lane];
    float r0 = n0 * c - n1 * s;
    float r1 = n1 * c + n0 * s;
    if (isQ) {
        qH[(size_t)row_i * HD_ + lane]      = (_Float16)(r0 * (1.0f / 128.0f));
        qH[(size_t)row_i * HD_ + lane + 64] = (_Float16)(r1 * (1.0f / 128.0f));
    } else {
        row[lane]      = r0;
        row[lane + 64] = r1;
    }
}

// ---------------- pack K+V into combined padded f16 tile image (64-key tiles) ----------------
__global__ void __launch_bounds__(256) pack_kv(const float* __restrict__ kf,
                                               const float* __restrict__ vf,
                                               _Float16* __restrict__ img) {
    int bid = blockIdx.x;
    int tile = bid & 31, g = (bid >> 5) & 3, b = bid >> 7;
    int tid = threadIdx.x;
    _Float16* out = img + (size_t)bid * (KV_TILE_BYTES / 2);

    // K part: 64 rows x 17 granules (granule 16 = pad)
    #pragma unroll
    for (int it = 0; it < 5; it++) {
        int gi = tid + 256 * it;
        if (gi < 64 * 17) {
            int key = gi / 17, gr = gi % 17;
            half8 hv = (half8){0, 0, 0, 0, 0, 0, 0, 0};
            if (gr < 16) {
                const float* src = kf + ((size_t)((b * T_ + tile * 64 + key) * G_ + g)) * HD_ + gr * 8;
                #pragma unroll
                for (int j = 0; j < 8; j++) hv[j] = (_Float16)src[j];
            }
            *(half8*)(out + (size_t)gi * 8) = hv;
        }
    }
    // V^T part: 128 rows (d) x 9 granules (granule 8 = pad); strided gather transpose
    #pragma unroll
    for (int it = 0; it < 5; it++) {
        int vi = tid + 256 * it;
        if (vi < 128 * 9) {
            int d = vi / 9, gr = vi % 9;
            half8 hv = (half8){0, 0, 0, 0, 0, 0, 0, 0};
            if (gr < 8) {
                const float* src = vf + ((size_t)((b * T_ + tile * 64 + gr * 8) * G_ + g)) * HD_ + d;
                #pragma unroll
                for (int j = 0; j < 8; j++) hv[j] = (_Float16)src[(size_t)j * (G_ * HD_)];
            }
            *(half8*)(out + VBASE_F16 + (size_t)vi * 8) = hv;
        }
    }
}

// ---------------- causal GQA flash attention v5 (R9-exact, measured 73.3 us) ----------------
// 32x32x16 MFMA, swapped QK^T, in-register softmax + P (T12), defer-max (T13),
// 2-deep counted-vmcnt staging pipeline: 9 x 1024B groups per wave per tile.
__global__ void __launch_bounds__(256, 2) attn_mfma5(const _Float16* __restrict__ qh,
                                                     const _Float16* __restrict__ kvimg,
                                                     _Float16* __restrict__ ctx) {
    int id = blockIdx.x;
    int hlf = id >> 8, rr0 = id & 255;
    int qb = hlf ? (15 - (rr0 & 15)) : (rr0 & 15);
    int hb = (rr0 >> 4) | (hlf << 4);
    int h = hb & 15, b = hb >> 4;
    int g = h >> 2;

    int tid = threadIdx.x;
    int w = tid >> 6, lane = tid & 63;
    int l31 = lane & 31, hi = lane >> 5;

    __shared__ __align__(16) char sKV[2][KV_TILE_BYTES];

    int qW = qb * 128 + w * 32;
    int qme = qW + l31;

    half8 qfrag[8];
    {
        const _Float16* qrow = qh + ((size_t)(b * T_ + qme)) * (H_ * HD_) + h * HD_ + hi * 8;
        #pragma unroll
        for (int ks = 0; ks < 8; ks++) qfrag[ks] = *(const half8*)(qrow + ks * 16);
    }

    f32x16 o[4];
    #pragma unroll
    for (int dt2 = 0; dt2 < 4; dt2++)
        #pragma unroll
        for (int r = 0; r < 16; r++) o[dt2][r] = 0.f;
    float m = -INFINITY, lsum = 0.f;

    const char* ibase = (const char*)kvimg + (size_t)((b * 4 + g) * 32) * KV_TILE_BYTES;

    // 36 groups of 1024B per tile; wave w takes groups w, w+4, ..., w+32 (9 each)
    #define STAGE_T(BUF, KT)                                                                       \
        do {                                                                                       \
            const char* src_ = ibase + (size_t)(KT) * KV_TILE_BYTES;                               \
            char* dst_ = &sKV[BUF][0];                                                             \
            _Pragma("unroll")                                                                      \
            for (int i_ = 0; i_ < 9; i_++) {                                                       \
                int c_ = w + 4 * i_;                                                               \
                __builtin_amdgcn_global_load_lds(                                                  \
                    (const __attribute__((address_space(1))) unsigned int*)(src_ + c_ * 1024 + lane * 16), \
                    (__attribute__((address_space(3))) unsigned int*)(dst_ + c_ * 1024 + lane * 16), 16, 0, 0); \
            }                                                                                      \
        } while (0)

    int nt = 2 * qb + 2;
    int ktmax_w = (qW + 31) >> 6;

    STAGE_T(0, 0);
    STAGE_T(1, 1);      // nt >= 2 always

    for (int kt = 0; kt < nt; kt++) {
        int cur = kt & 1;
        if (kt + 1 < nt) asm volatile("s_waitcnt vmcnt(9)" ::: "memory");
        else             asm volatile("s_waitcnt vmcnt(0)" ::: "memory");
        __builtin_amdgcn_sched_barrier(0);
        __builtin_amdgcn_s_barrier();      // all waves' tile-kt loads landed
        __builtin_amdgcn_sched_barrier(0);

        if (kt <= ktmax_w) {
            const char* bufK = &sKV[cur][0];
            const char* bufV = &sKV[cur][0] + VBASE_F16 * 2;

            f32x16 stc[2];
            #pragma unroll
            for (int kt2 = 0; kt2 < 2; kt2++)
                #pragma unroll
                for (int r = 0; r < 16; r++) stc[kt2][r] = 0.f;

            __builtin_amdgcn_s_setprio(1);
            #pragma unroll
            for (int ks = 0; ks < 8; ks++) {
                #pragma unroll
                for (int kt2 = 0; kt2 < 2; kt2++) {
                    half8 kfr = *(const half8*)(bufK + (kt2 * 32 + l31) * (KROW_F16 * 2) + ks * 32 + hi * 16);
                    stc[kt2] = __builtin_amdgcn_mfma_f32_32x32x16_f16(kfr, qfrag[ks], stc[kt2], 0, 0, 0);
                }
            }
            __builtin_amdgcn_s_setprio(0);

            #pragma unroll
            for (int kt2 = 0; kt2 < 2; kt2++)
                #pragma unroll
                for (int reg = 0; reg < 16; reg++) {
                    int key = kt * 64 + kt2 * 32 + 8 * (reg >> 2) + 4 * hi + (reg & 3);
                    float v = stc[kt2][reg];
                    stc[kt2][reg] = (key <= qme) ? v : -INFINITY;
                }

            float pmax = -INFINITY;
            #pragma unroll
            for (int kt2 = 0; kt2 < 2; kt2++)
                #pragma unroll
                for (int reg = 0; reg < 16; reg++) pmax = fmaxf(pmax, stc[kt2][reg]);
            pmax = fmaxf(pmax, __shfl_xor(pmax, 32));

            if (__any(!(pmax - m <= 8.0f))) {
                float nm = fmaxf(m, pmax);
                float alpha = __expf(m - nm);
                lsum *= alpha;
                #pragma unroll
                for (int reg = 0; reg < 16; reg++) {
                    float ar = __shfl(alpha, 8 * (reg >> 2) + 4 * hi + (reg & 3));
                    #pragma unroll
                    for (int dt2 = 0; dt2 < 4; dt2++) o[dt2][reg] *= ar;
                }
                m = nm;
            }

            float rsum = 0.f;
            #pragma unroll
            for (int kt2 = 0; kt2 < 2; kt2++)
                #pragma unroll
                for (int reg = 0; reg < 16; reg++) {
                    float e = __expf(stc[kt2][reg] - m);
                    stc[kt2][reg] = e;
                    rsum += e;
                }
            rsum += __shfl_xor(rsum, 32);
            lsum += rsum;

            int pk[16];
            #pragma unroll
            for (int kt2 = 0; kt2 < 2; kt2++)
                #pragma unroll
                for (int oo = 0; oo < 4; oo++)
                    #pragma unroll
                    for (int c = 0; c < 2; c++) {
                        half2_t hp;
                        hp[0] = (_Float16)stc[kt2][4 * oo + 2 * c];
                        hp[1] = (_Float16)stc[kt2][4 * oo + 2 * c + 1];
                        pk[kt2 * 8 + 2 * oo + c] = __builtin_bit_cast(int, hp);
                    }

            __builtin_amdgcn_s_setprio(1);
            #pragma unroll
            for (int ks = 0; ks < 4; ks++) {
                int base = (ks >> 1) * 8 + (ks & 1) * 4;
                int z0 = hi ? pk[base + 0] : pk[base + 2];
                int z1 = hi ? pk[base + 1] : pk[base + 3];
                int xz0 = __shfl_xor(z0, 32);
                int xz1 = __shfl_xor(z1, 32);
                int4_t pi;
                pi[0] = hi ? xz0 : pk[base + 0];
                pi[1] = hi ? xz1 : pk[base + 1];
                pi[2] = hi ? pk[base + 2] : xz0;
                pi[3] = hi ? pk[base + 3] : xz1;
                half8 pfrag = __builtin_bit_cast(half8, pi);
                #pragma unroll
                for (int dt2 = 0; dt2 < 4; dt2++) {
                    half8 vfr = *(const half8*)(bufV + (dt2 * 32 + l31) * (VROW_F16 * 2) + ks * 32 + hi * 16);
                    o[dt2] = __builtin_amdgcn_mfma_f32_32x32x16_f16(pfrag, vfr, o[dt2], 0, 0, 0);
                }
            }
            __builtin_amdgcn_s_setprio(0);
        }

        __builtin_amdgcn_sched_barrier(0);
        asm volatile("" ::: "memory");     // pin LDS reads above the barrier
        __builtin_amdgcn_s_barrier();      // all waves done reading buf[cur]
        __builtin_amdgcn_sched_barrier(0);
        if (kt + 2 < nt) STAGE_T(cur, kt + 2);
    }
    #undef STAGE_T

    float invl = 1.0f / lsum;
    #pragma unroll
    for (int reg = 0; reg < 16; reg++) {
        int qrow = 8 * (reg >> 2) + 4 * hi + (reg & 3);
        float ir = __shfl(invl, qrow);
        _Float16* orow = ctx + (size_t)(b * T_ + qW + qrow) * (H_ * HD_) + h * HD_ + l31;
        #pragma unroll
        for (int dt2 = 0; dt2 < 4; dt2++)
            orow[dt2 * 32] = (_Float16)(o[dt2][reg] * ir);
    }
}

// ---------------- launch ----------------
extern "C" void kernel_launch(void* const* d_in, const int* in_sizes, int n_in,
                              void* d_out, int out_size, void* d_ws, size_t ws_size,
                              hipStream_t stream) {
    const float* x   = (const float*)d_in[0];
    const float* Wq  = (const float*)d_in[1];
    const float* Wk  = (const float*)d_in[2];
    const float* Wv  = (const float*)d_in[3];
    const float* Wo  = (const float*)d_in[4];
    const float* qnw = (const float*)d_in[5];
    const float* knw = (const float*)d_in[6];
    float* out = (float*)d_out;

    char* ws = (char*)d_ws;
    size_t off = 0;
    auto alloc = [&](size_t bytes) {
        char* p = ws + off;
        off += (bytes + 255) & ~(size_t)255;
        return p;
    };
    _Float16* x_h  = (_Float16*)alloc((size_t)B_ * T_ * D_ * 2);        // reused as q_h
    _Float16* wq_h = (_Float16*)alloc((size_t)H_ * HD_ * D_ * 2);       // reused as kvimg (with wk_h)
    _Float16* wk_h = (_Float16*)alloc((size_t)G_ * HD_ * D_ * 2);
    _Float16* wv_h = (_Float16*)alloc((size_t)G_ * HD_ * D_ * 2);
    _Float16* wo_h = (_Float16*)alloc((size_t)D_ * H_ * HD_ * 2);
    float* q_f = (float*)alloc((size_t)B_ * T_ * H_ * HD_ * 4);
    float* k_f = (float*)alloc((size_t)B_ * T_ * G_ * HD_ * 4);
    float* v_f = (float*)alloc((size_t)B_ * T_ * G_ * HD_ * 4);
    _Float16* ctx_h = (_Float16*)alloc((size_t)B_ * T_ * H_ * HD_ * 2);
    float* cosT = (float*)alloc((size_t)T_ * 64 * 4);
    float* sinT = (float*)alloc((size_t)T_ * 64 * 4);

    // aliases (lifetimes disjoint):
    _Float16* q_h   = x_h;     // x_h dead after QKV GEMM
    _Float16* kvimg = wq_h;    // wq_h+wk_h dead after QKV GEMM; image = 256*36864 = 9.4 MB

    // fused vectorized conversions + rope tables
    cvt_all<<<2048, 256, 0, stream>>>(x, Wq, Wk, Wv, Wo, x_h, wq_h, wk_h, wv_h, wo_h);
    rope_tables_k<<<(T_ * 64) / 256, 256, 0, stream>>>(cosT, sinT);

    // fused Q+K+V projection: 128x128 tiles, 3-deep counted-vmcnt pipeline
    gemm_tile<<<dim3(32, 24), 256, 0, stream>>>(x_h, wq_h, q_f, 16,
                                                wk_h, k_f, 4,
                                                wv_h, v_f, 4, D_);

    // fused Q+K norm+rope (Q -> f16 with 1/128 scale; K in-place f32)
    rmsnorm_rope_qk<<<(B_ * T_ * (H_ + G_)) / 4, 256, 0, stream>>>(q_f, k_f, qnw, knw, cosT, sinT, q_h);

    // pack K/V into combined padded f16 tile images (64-key tiles)
    pack_kv<<<256, 256, 0, stream>>>(k_f, v_f, kvimg);

    // causal GQA attention -> ctx (f16)
    attn_mfma5<<<512, 256, 0, stream>>>(q_h, kvimg, ctx_h);

    // output projection: 128x128 tiles, 3-deep counted-vmcnt pipeline
    gemm_tile<<<dim3(32, 16), 256, 0, stream>>>(ctx_h, wo_h, out, 16,
                                                nullptr, nullptr, 0,
                                                nullptr, nullptr, 0, H_ * HD_);
}

// Round 16
// 214.215 us; speedup vs baseline: 1.3080x; 1.0251x over previous
//
#include <hip/hip_runtime.h>
#include <hip/hip_bf16.h>

// Problem constants (match reference)
#define B_ 2
#define T_ 2048
#define D_ 2048
#define H_ 16
#define G_ 4
#define HD_ 128
#define GS_ (H_/G_)

typedef _Float16 half8 __attribute__((ext_vector_type(8)));
typedef _Float16 half2_t __attribute__((ext_vector_type(2)));
typedef float f32x4 __attribute__((ext_vector_type(4)));
typedef float f32x16 __attribute__((ext_vector_type(16)));
typedef int int4_t __attribute__((ext_vector_type(4)));

// Combined KV tile image: per (b,g,tile64): [K: 64 rows x 136 f16 (128 data + 8 pad)]
// then [V^T: 128 rows x 72 f16 (64 data + 8 pad)], padded to 36864 B so each of the
// 4 waves stages exactly 9 x 1024B groups (uniform vmcnt counting).
#define KV_TILE_BYTES 36864
#define KROW_F16 136
#define VROW_F16 72
#define VBASE_F16 8704   // 17408 bytes / 2

// ---------------- fused conversions (x, Wq, Wk, Wv, Wo) + RoPE tables ----------------
// Blocks 0..2047: grid-stride f32->f16 conversion over all 5 tensors.
// Blocks 2048..2559: cos/sin tables (T_*64 = 131072 entries).
#define C0_ 1048576   // x:  8388608/8
#define C1_ 1572864   // +Wq 4194304/8
#define C2_ 1703936   // +Wk 1048576/8
#define C3_ 1835008   // +Wv 1048576/8
#define C4_ 2359296   // +Wo 4194304/8
__global__ void cvt_rope(const float* __restrict__ sx, const float* __restrict__ sq,
                         const float* __restrict__ sk, const float* __restrict__ sv,
                         const float* __restrict__ so,
                         _Float16* __restrict__ dx, _Float16* __restrict__ dq,
                         _Float16* __restrict__ dk, _Float16* __restrict__ dv,
                         _Float16* __restrict__ dw,
                         float* __restrict__ cosT, float* __restrict__ sinT) {
    int blk = blockIdx.x, tid = threadIdx.x;
    if (blk < 2048) {
        int g = blk * 256 + tid;
        for (; g < C4_; g += 2048 * 256) {
            const float* src; _Float16* dst; int local;
            if (g < C0_)      { src = sx; dst = dx; local = g; }
            else if (g < C1_) { src = sq; dst = dq; local = g - C0_; }
            else if (g < C2_) { src = sk; dst = dk; local = g - C1_; }
            else if (g < C3_) { src = sv; dst = dv; local = g - C2_; }
            else              { src = so; dst = dw; local = g - C3_; }
            f32x4 a = *((const f32x4*)src + local * 2);
            f32x4 b = *((const f32x4*)src + local * 2 + 1);
            half8 hv;
            hv[0] = (_Float16)a[0]; hv[1] = (_Float16)a[1];
            hv[2] = (_Float16)a[2]; hv[3] = (_Float16)a[3];
            hv[4] = (_Float16)b[0]; hv[5] = (_Float16)b[1];
            hv[6] = (_Float16)b[2]; hv[7] = (_Float16)b[3];
            *((half8*)dst + local) = hv;
        }
    } else {
        int i = (blk - 2048) * 256 + tid;   // 0 .. 131071
        int t = i >> 6, l = i & 63;
        float inv_freq = powf(10000.0f, -((float)(2 * l)) / 128.0f);
        float a = (float)t * inv_freq;
        cosT[i] = cosf(a);
        sinT[i] = sinf(a);
    }
}

// ---------------- Tiled TN GEMM, 128x128 tile, 2-deep counted-vmcnt pipeline (R9) ----------------
__global__ void __launch_bounds__(256) gemm_tile(const _Float16* __restrict__ A,
                                                 const _Float16* __restrict__ B0,
                                                 float* __restrict__ C0, int n0t,
                                                 const _Float16* __restrict__ B1,
                                                 float* __restrict__ C1, int n1t,
                                                 const _Float16* __restrict__ B2,
                                                 float* __restrict__ C2, int n2t,
                                                 int Kd) {
    __shared__ _Float16 sA[2][128 * 32];
    __shared__ _Float16 sB[2][128 * 32];

    int tid = threadIdx.x;
    int w = tid >> 6, lane = tid & 63;
    int l15 = lane & 15, g4 = lane >> 4;
    int wm = w >> 1, wn = w & 1;

    int y = blockIdx.y;
    const _Float16* Bsel;
    float* Csel;
    int ldc, cb;
    if (y < n0t)            { Bsel = B0; Csel = C0; ldc = n0t * 128; cb = y; }
    else if (y < n0t + n1t) { Bsel = B1; Csel = C1; ldc = n1t * 128; cb = y - n0t; }
    else                    { Bsel = B2; Csel = C2; ldc = n2t * 128; cb = y - n0t - n1t; }

    const _Float16* Ab = A + (size_t)(blockIdx.x * 128) * Kd;
    const _Float16* Bb = Bsel + (size_t)(cb * 128) * Kd;

    int s0 = w * 128 + lane;
    int s1 = s0 + 64;
    size_t ga0 = (size_t)(s0 >> 2) * Kd + (s0 & 3) * 8;
    size_t ga1 = (size_t)(s1 >> 2) * Kd + (s1 & 3) * 8;

    #define STAGE(BUF, K0)                                                                     \
        do {                                                                                   \
            _Float16* a0_ = &sA[BUF][0] + (size_t)(w * 2) * 512;                               \
            _Float16* a1_ = &sA[BUF][0] + (size_t)(w * 2 + 1) * 512;                           \
            _Float16* b0_ = &sB[BUF][0] + (size_t)(w * 2) * 512;                               \
            _Float16* b1_ = &sB[BUF][0] + (size_t)(w * 2 + 1) * 512;                           \
            __builtin_amdgcn_global_load_lds(                                                  \
                (const __attribute__((address_space(1))) unsigned int*)(Ab + ga0 + (K0)),      \
                (__attribute__((address_space(3))) unsigned int*)a0_, 16, 0, 0);               \
            __builtin_amdgcn_global_load_lds(                                                  \
                (const __attribute__((address_space(1))) unsigned int*)(Ab + ga1 + (K0)),      \
                (__attribute__((address_space(3))) unsigned int*)a1_, 16, 0, 0);               \
            __builtin_amdgcn_global_load_lds(                                                  \
                (const __attribute__((address_space(1))) unsigned int*)(Bb + ga0 + (K0)),      \
                (__attribute__((address_space(3))) unsigned int*)b0_, 16, 0, 0);               \
            __builtin_amdgcn_global_load_lds(                                                  \
                (const __attribute__((address_space(1))) unsigned int*)(Bb + ga1 + (K0)),      \
                (__attribute__((address_space(3))) unsigned int*)b1_, 16, 0, 0);               \
        } while (0)

    f32x4 acc[4][4];
    #pragma unroll
    for (int i = 0; i < 4; i++)
        #pragma unroll
        for (int j = 0; j < 4; j++) acc[i][j] = (f32x4){0.f, 0.f, 0.f, 0.f};

    int nIt = Kd >> 5;
    STAGE(0, 0);
    if (nIt > 1) STAGE(1, 32);

    for (int it = 0; it < nIt; ++it) {
        int cur = it & 1;
        if (it + 1 < nIt) asm volatile("s_waitcnt vmcnt(4)" ::: "memory");
        else              asm volatile("s_waitcnt vmcnt(0)" ::: "memory");
        __builtin_amdgcn_sched_barrier(0);
        __builtin_amdgcn_s_barrier();          // all waves' tile-it loads landed
        __builtin_amdgcn_sched_barrier(0);

        half8 af[4], bf[4];
        #pragma unroll
        for (int mi = 0; mi < 4; mi++)
            af[mi] = *(const half8*)&sA[cur][(wm * 64 + mi * 16 + l15) * 32 + g4 * 8];
        #pragma unroll
        for (int ni = 0; ni < 4; ni++)
            bf[ni] = *(const half8*)&sB[cur][(wn * 64 + ni * 16 + l15) * 32 + g4 * 8];

        #pragma unroll
        for (int mi = 0; mi < 4; mi++)
            #pragma unroll
            for (int ni = 0; ni < 4; ni++)
                acc[mi][ni] = __builtin_amdgcn_mfma_f32_16x16x32_f16(af[mi], bf[ni], acc[mi][ni], 0, 0, 0);

        __builtin_amdgcn_sched_barrier(0);
        asm volatile("" ::: "memory");         // pin LDS reads above the barrier
        __builtin_amdgcn_s_barrier();          // all waves done reading buf[cur]
        __builtin_amdgcn_sched_barrier(0);
        if (it + 2 < nIt) STAGE(cur, (size_t)(it + 2) * 32);
    }
    #undef STAGE

    int rbase = blockIdx.x * 128 + wm * 64 + g4 * 4;
    int cbase = cb * 128 + wn * 64 + l15;
    #pragma unroll
    for (int mi = 0; mi < 4; mi++)
        #pragma unroll
        for (int r = 0; r < 4; r++) {
            float* crow = Csel + (size_t)(rbase + mi * 16 + r) * ldc + cbase;
            #pragma unroll
            for (int ni = 0; ni < 4; ni++) crow[ni * 16] = acc[mi][ni][r];
        }
}

// ---------------- fused RMSNorm+RoPE (Q,K) + V-transpose pack, one dispatch ----------------
// Blocks 0..16383:   Q rows (65536; norm+rope -> f16 q_h with 1/128 scale)
// Blocks 16384..20479: K rows (16384; norm+rope -> f16 DIRECTLY into KV image K-part)
// Blocks 20480..20735: V-transpose into KV image V-part (256 records)
// (K-part pad granule holds garbage — never read by QK^T fragments.)
__global__ void __launch_bounds__(256) norm_pack(const float* __restrict__ Qf,
                                                 const float* __restrict__ Kf,
                                                 const float* __restrict__ vf,
                                                 const float* __restrict__ qw,
                                                 const float* __restrict__ kw,
                                                 const float* __restrict__ cosT,
                                                 const float* __restrict__ sinT,
                                                 _Float16* __restrict__ qH,
                                                 _Float16* __restrict__ img) {
    int blk = blockIdx.x, tid = threadIdx.x;
    if (blk < 20480) {
        int gw = (blk * 256 + tid) >> 6;
        int lane = tid & 63;
        bool isQ = gw < (B_ * T_ * H_);
        int row_i = isQ ? gw : gw - (B_ * T_ * H_);
        int heads = isQ ? H_ : G_;
        const float* wv = isQ ? qw : kw;
        const float* row = (isQ ? Qf : Kf) + (size_t)row_i * HD_;
        int t = (row_i / heads) % T_;
        float x0 = row[lane];
        float x1 = row[lane + 64];
        float ss = x0 * x0 + x1 * x1;
        #pragma unroll
        for (int off = 1; off < 64; off <<= 1) ss += __shfl_xor(ss, off);
        float inv = rsqrtf(ss * (1.0f / 128.0f) + 1e-6f);
        float n0 = x0 * inv * wv[lane];
        float n1 = x1 * inv * wv[lane + 64];
        float c = cosT[t * 64 + lane];
        float s = sinT[t * 64 + lane];
        float r0 = n0 * c - n1 * s;
        float r1 = n1 * c + n0 * s;
        if (isQ) {
            qH[(size_t)row_i * HD_ + lane]      = (_Float16)(r0 * (1.0f / 128.0f));
            qH[(size_t)row_i * HD_ + lane + 64] = (_Float16)(r1 * (1.0f / 128.0f));
        } else {
            // row_i = (b*T + t)*G + g  ->  image record (b*4+g)*32 + (t>>6), key = t&63
            int b = row_i / (T_ * G_);
            int rem = row_i - b * (T_ * G_);
            int g = rem - (rem / G_) * G_;
            int bid = (b * 4 + g) * 32 + (t >> 6);
            _Float16* kout = img + (size_t)bid * (KV_TILE_BYTES / 2) + (t & 63) * KROW_F16;
            kout[lane]      = (_Float16)r0;
            kout[lane + 64] = (_Float16)r1;
        }
    } else {
        // V^T part: record vb; 128 rows (d) x 9 granules (granule 8 = pad)
        int vb = blk - 20480;
        int tile = vb & 31, g = (vb >> 5) & 3, b = vb >> 7;
        _Float16* out = img + (size_t)vb * (KV_TILE_BYTES / 2);
        #pragma unroll
        for (int it = 0; it < 5; it++) {
            int vi = tid + 256 * it;
            if (vi < 128 * 9) {
                int d = vi / 9, gr = vi % 9;
                half8 hv = (half8){0, 0, 0, 0, 0, 0, 0, 0};
                if (gr < 8) {
                    const float* src = vf + ((size_t)((b * T_ + tile * 64 + gr * 8) * G_ + g)) * HD_ + d;
                    #pragma unroll
                    for (int j = 0; j < 8; j++) hv[j] = (_Float16)src[(size_t)j * (G_ * HD_)];
                }
                *(half8*)(out + VBASE_F16 + (size_t)vi * 8) = hv;
            }
        }
    }
}

// ---------------- causal GQA flash attention v5 (R9-exact, measured 73.3 us) ----------------
__global__ void __launch_bounds__(256, 2) attn_mfma5(const _Float16* __restrict__ qh,
                                                     const _Float16* __restrict__ kvimg,
                                                     _Float16* __restrict__ ctx) {
    int id = blockIdx.x;
    int hlf = id >> 8, rr0 = id & 255;
    int qb = hlf ? (15 - (rr0 & 15)) : (rr0 & 15);
    int hb = (rr0 >> 4) | (hlf << 4);
    int h = hb & 15, b = hb >> 4;
    int g = h >> 2;

    int tid = threadIdx.x;
    int w = tid >> 6, lane = tid & 63;
    int l31 = lane & 31, hi = lane >> 5;

    __shared__ __align__(16) char sKV[2][KV_TILE_BYTES];

    int qW = qb * 128 + w * 32;
    int qme = qW + l31;

    half8 qfrag[8];
    {
        const _Float16* qrow = qh + ((size_t)(b * T_ + qme)) * (H_ * HD_) + h * HD_ + hi * 8;
        #pragma unroll
        for (int ks = 0; ks < 8; ks++) qfrag[ks] = *(const half8*)(qrow + ks * 16);
    }

    f32x16 o[4];
    #pragma unroll
    for (int dt2 = 0; dt2 < 4; dt2++)
        #pragma unroll
        for (int r = 0; r < 16; r++) o[dt2][r] = 0.f;
    float m = -INFINITY, lsum = 0.f;

    const char* ibase = (const char*)kvimg + (size_t)((b * 4 + g) * 32) * KV_TILE_BYTES;

    // 36 groups of 1024B per tile; wave w takes groups w, w+4, ..., w+32 (9 each)
    #define STAGE_T(BUF, KT)                                                                       \
        do {                                                                                       \
            const char* src_ = ibase + (size_t)(KT) * KV_TILE_BYTES;                               \
            char* dst_ = &sKV[BUF][0];                                                             \
            _Pragma("unroll")                                                                      \
            for (int i_ = 0; i_ < 9; i_++) {                                                       \
                int c_ = w + 4 * i_;                                                               \
                __builtin_amdgcn_global_load_lds(                                                  \
                    (const __attribute__((address_space(1))) unsigned int*)(src_ + c_ * 1024 + lane * 16), \
                    (__attribute__((address_space(3))) unsigned int*)(dst_ + c_ * 1024 + lane * 16), 16, 0, 0); \
            }                                                                                      \
        } while (0)

    int nt = 2 * qb + 2;
    int ktmax_w = (qW + 31) >> 6;

    STAGE_T(0, 0);
    STAGE_T(1, 1);      // nt >= 2 always

    for (int kt = 0; kt < nt; kt++) {
        int cur = kt & 1;
        if (kt + 1 < nt) asm volatile("s_waitcnt vmcnt(9)" ::: "memory");
        else             asm volatile("s_waitcnt vmcnt(0)" ::: "memory");
        __builtin_amdgcn_sched_barrier(0);
        __builtin_amdgcn_s_barrier();      // all waves' tile-kt loads landed
        __builtin_amdgcn_sched_barrier(0);

        if (kt <= ktmax_w) {
            const char* bufK = &sKV[cur][0];
            const char* bufV = &sKV[cur][0] + VBASE_F16 * 2;

            f32x16 stc[2];
            #pragma unroll
            for (int kt2 = 0; kt2 < 2; kt2++)
                #pragma unroll
                for (int r = 0; r < 16; r++) stc[kt2][r] = 0.f;

            __builtin_amdgcn_s_setprio(1);
            #pragma unroll
            for (int ks = 0; ks < 8; ks++) {
                #pragma unroll
                for (int kt2 = 0; kt2 < 2; kt2++) {
                    half8 kfr = *(const half8*)(bufK + (kt2 * 32 + l31) * (KROW_F16 * 2) + ks * 32 + hi * 16);
                    stc[kt2] = __builtin_amdgcn_mfma_f32_32x32x16_f16(kfr, qfrag[ks], stc[kt2], 0, 0, 0);
                }
            }
            __builtin_amdgcn_s_setprio(0);

            #pragma unroll
            for (int kt2 = 0; kt2 < 2; kt2++)
                #pragma unroll
                for (int reg = 0; reg < 16; reg++) {
                    int key = kt * 64 + kt2 * 32 + 8 * (reg >> 2) + 4 * hi + (reg & 3);
                    float v = stc[kt2][reg];
                    stc[kt2][reg] = (key <= qme) ? v : -INFINITY;
                }

            float pmax = -INFINITY;
            #pragma unroll
            for (int kt2 = 0; kt2 < 2; kt2++)
                #pragma unroll
                for (int reg = 0; reg < 16; reg++) pmax = fmaxf(pmax, stc[kt2][reg]);
            pmax = fmaxf(pmax, __shfl_xor(pmax, 32));

            if (__any(!(pmax - m <= 8.0f))) {
                float nm = fmaxf(m, pmax);
                float alpha = __expf(m - nm);
                lsum *= alpha;
                #pragma unroll
                for (int reg = 0; reg < 16; reg++) {
                    float ar = __shfl(alpha, 8 * (reg >> 2) + 4 * hi + (reg & 3));
                    #pragma unroll
                    for (int dt2 = 0; dt2 < 4; dt2++) o[dt2][reg] *= ar;
                }
                m = nm;
            }

            float rsum = 0.f;
            #pragma unroll
            for (int kt2 = 0; kt2 < 2; kt2++)
                #pragma unroll
                for (int reg = 0; reg < 16; reg++) {
                    float e = __expf(stc[kt2][reg] - m);
                    stc[kt2][reg] = e;
                    rsum += e;
                }
            rsum += __shfl_xor(rsum, 32);
            lsum += rsum;

            int pk[16];
            #pragma unroll
            for (int kt2 = 0; kt2 < 2; kt2++)
                #pragma unroll
                for (int oo = 0; oo < 4; oo++)
                    #pragma unroll
                    for (int c = 0; c < 2; c++) {
                        half2_t hp;
                        hp[0] = (_Float16)stc[kt2][4 * oo + 2 * c];
                        hp[1] = (_Float16)stc[kt2][4 * oo + 2 * c + 1];
                        pk[kt2 * 8 + 2 * oo + c] = __builtin_bit_cast(int, hp);
                    }

            __builtin_amdgcn_s_setprio(1);
            #pragma unroll
            for (int ks = 0; ks < 4; ks++) {
                int base = (ks >> 1) * 8 + (ks & 1) * 4;
                int z0 = hi ? pk[base + 0] : pk[base + 2];
                int z1 = hi ? pk[base + 1] : pk[base + 3];
                int xz0 = __shfl_xor(z0, 32);
                int xz1 = __shfl_xor(z1, 32);
                int4_t pi;
                pi[0] = hi ? xz0 : pk[base + 0];
                pi[1] = hi ? xz1 : pk[base + 1];
                pi[2] = hi ? pk[base + 2] : xz0;
                pi[3] = hi ? pk[base + 3] : xz1;
                half8 pfrag = __builtin_bit_cast(half8, pi);
                #pragma unroll
                for (int dt2 = 0; dt2 < 4; dt2++) {
                    half8 vfr = *(const half8*)(bufV + (dt2 * 32 + l31) * (VROW_F16 * 2) + ks * 32 + hi * 16);
                    o[dt2] = __builtin_amdgcn_mfma_f32_32x32x16_f16(pfrag, vfr, o[dt2], 0, 0, 0);
                }
            }
            __builtin_amdgcn_s_setprio(0);
        }

        __builtin_amdgcn_sched_barrier(0);
        asm volatile("" ::: "memory");     // pin LDS reads above the barrier
        __builtin_amdgcn_s_barrier();      // all waves done reading buf[cur]
        __builtin_amdgcn_sched_barrier(0);
        if (kt + 2 < nt) STAGE_T(cur, kt + 2);
    }
    #undef STAGE_T

    float invl = 1.0f / lsum;
    #pragma unroll
    for (int reg = 0; reg < 16; reg++) {
        int qrow = 8 * (reg >> 2) + 4 * hi + (reg & 3);
        float ir = __shfl(invl, qrow);
        _Float16* orow = ctx + (size_t)(b * T_ + qW + qrow) * (H_ * HD_) + h * HD_ + l31;
        #pragma unroll
        for (int dt2 = 0; dt2 < 4; dt2++)
            orow[dt2 * 32] = (_Float16)(o[dt2][reg] * ir);
    }
}

// ---------------- launch ----------------
extern "C" void kernel_launch(void* const* d_in, const int* in_sizes, int n_in,
                              void* d_out, int out_size, void* d_ws, size_t ws_size,
                              hipStream_t stream) {
    const float* x   = (const float*)d_in[0];
    const float* Wq  = (const float*)d_in[1];
    const float* Wk  = (const float*)d_in[2];
    const float* Wv  = (const float*)d_in[3];
    const float* Wo  = (const float*)d_in[4];
    const float* qnw = (const float*)d_in[5];
    const float* knw = (const float*)d_in[6];
    float* out = (float*)d_out;

    char* ws = (char*)d_ws;
    size_t off = 0;
    auto alloc = [&](size_t bytes) {
        char* p = ws + off;
        off += (bytes + 255) & ~(size_t)255;
        return p;
    };
    _Float16* x_h  = (_Float16*)alloc((size_t)B_ * T_ * D_ * 2);        // reused as q_h
    _Float16* wq_h = (_Float16*)alloc((size_t)H_ * HD_ * D_ * 2);       // reused as kvimg (with wk_h)
    _Float16* wk_h = (_Float16*)alloc((size_t)G_ * HD_ * D_ * 2);
    _Float16* wv_h = (_Float16*)alloc((size_t)G_ * HD_ * D_ * 2);
    _Float16* wo_h = (_Float16*)alloc((size_t)D_ * H_ * HD_ * 2);
    float* q_f = (float*)alloc((size_t)B_ * T_ * H_ * HD_ * 4);
    float* k_f = (float*)alloc((size_t)B_ * T_ * G_ * HD_ * 4);
    float* v_f = (float*)alloc((size_t)B_ * T_ * G_ * HD_ * 4);
    _Float16* ctx_h = (_Float16*)alloc((size_t)B_ * T_ * H_ * HD_ * 2);
    float* cosT = (float*)alloc((size_t)T_ * 64 * 4);
    float* sinT = (float*)alloc((size_t)T_ * 64 * 4);

    // aliases (lifetimes disjoint):
    _Float16* q_h   = x_h;     // x_h dead after QKV GEMM
    _Float16* kvimg = wq_h;    // wq_h+wk_h dead after QKV GEMM; image = 256*36864 = 9.4 MB

    // fused conversions + rope tables (one dispatch)
    cvt_rope<<<2560, 256, 0, stream>>>(x, Wq, Wk, Wv, Wo, x_h, wq_h, wk_h, wv_h, wo_h,
                                       cosT, sinT);

    // fused Q+K+V projection: 128x128 tiles, 2-deep counted-vmcnt pipeline
    gemm_tile<<<dim3(32, 24), 256, 0, stream>>>(x_h, wq_h, q_f, 16,
                                                wk_h, k_f, 4,
                                                wv_h, v_f, 4, D_);

    // fused norm+rope (Q->q_h f16, K->KV image f16) + V-transpose pack (one dispatch)
    norm_pack<<<20736, 256, 0, stream>>>(q_f, k_f, v_f, qnw, knw, cosT, sinT, q_h, kvimg);

    // causal GQA attention -> ctx (f16)
    attn_mfma5<<<512, 256, 0, stream>>>(q_h, kvimg, ctx_h);

    // output projection: 128x128 tiles, 2-deep counted-vmcnt pipeline
    gemm_tile<<<dim3(32, 16), 256, 0, stream>>>(ctx_h, wo_h, out, 16,
                                                nullptr, nullptr, 0,
                                                nullptr, nullptr, 0, H_ * HD_);
}

// Round 17
// 208.000 us; speedup vs baseline: 1.3471x; 1.0299x over previous
//
#include <hip/hip_runtime.h>
#include <hip/hip_bf16.h>

// Problem constants (match reference)
#define B_ 2
#define T_ 2048
#define D_ 2048
#define H_ 16
#define G_ 4
#define HD_ 128
#define GS_ (H_/G_)

typedef _Float16 half8 __attribute__((ext_vector_type(8)));
typedef _Float16 half2_t __attribute__((ext_vector_type(2)));
typedef float f32x4 __attribute__((ext_vector_type(4)));
typedef float f32x16 __attribute__((ext_vector_type(16)));
typedef int int4_t __attribute__((ext_vector_type(4)));

// Combined KV tile image: per (b,g,tile64): [K: 64 rows x 136 f16 (128 data + 8 pad)]
// then [V^T: 128 rows x 72 f16 (64 data + 8 pad)], padded to 36864 B so each of the
// 4 waves stages exactly 9 x 1024B groups (uniform vmcnt counting).
#define KV_TILE_BYTES 36864
#define KROW_F16 136
#define VROW_F16 72
#define VBASE_F16 8704   // 17408 bytes / 2

// ---------------- fused conversions (x, Wq, Wk, Wv, Wo) + RoPE tables ----------------
#define C0_ 1048576   // x:  8388608/8
#define C1_ 1572864   // +Wq 4194304/8
#define C2_ 1703936   // +Wk 1048576/8
#define C3_ 1835008   // +Wv 1048576/8
#define C4_ 2359296   // +Wo 4194304/8
__global__ void cvt_rope(const float* __restrict__ sx, const float* __restrict__ sq,
                         const float* __restrict__ sk, const float* __restrict__ sv,
                         const float* __restrict__ so,
                         _Float16* __restrict__ dx, _Float16* __restrict__ dq,
                         _Float16* __restrict__ dk, _Float16* __restrict__ dv,
                         _Float16* __restrict__ dw,
                         float* __restrict__ cosT, float* __restrict__ sinT) {
    int blk = blockIdx.x, tid = threadIdx.x;
    if (blk < 2048) {
        int g = blk * 256 + tid;
        for (; g < C4_; g += 2048 * 256) {
            const float* src; _Float16* dst; int local;
            if (g < C0_)      { src = sx; dst = dx; local = g; }
            else if (g < C1_) { src = sq; dst = dq; local = g - C0_; }
            else if (g < C2_) { src = sk; dst = dk; local = g - C1_; }
            else if (g < C3_) { src = sv; dst = dv; local = g - C2_; }
            else              { src = so; dst = dw; local = g - C3_; }
            f32x4 a = *((const f32x4*)src + local * 2);
            f32x4 b = *((const f32x4*)src + local * 2 + 1);
            half8 hv;
            hv[0] = (_Float16)a[0]; hv[1] = (_Float16)a[1];
            hv[2] = (_Float16)a[2]; hv[3] = (_Float16)a[3];
            hv[4] = (_Float16)b[0]; hv[5] = (_Float16)b[1];
            hv[6] = (_Float16)b[2]; hv[7] = (_Float16)b[3];
            *((half8*)dst + local) = hv;
        }
    } else {
        int i = (blk - 2048) * 256 + tid;   // 0 .. 131071
        int t = i >> 6, l = i & 63;
        float inv_freq = powf(10000.0f, -((float)(2 * l)) / 128.0f);
        float a = (float)t * inv_freq;
        cosT[i] = cosf(a);
        sinT[i] = sinf(a);
    }
}

// ---------------- Tiled TN GEMM, 128x128 tile, 2-deep counted-vmcnt pipeline ----------------
// fuse=1 (QKV): y<16 -> Q: rmsnorm+rope epilogue -> f16 qH (1/128 scale);
//               16<=y<20 -> K: rmsnorm+rope epilogue -> f16 KV-image K-part;
//               y>=20 -> V: plain f32 C-write (to C2 = v_f).
// fuse=0 (Oproj): plain f32 C-write.
// Fused epilogue bounces the C tile through the dead staging LDS (32 KB) in two
// 64-row chunks; rotate-half pair (c, c+64) spans the two wn wave-halves.
__global__ void __launch_bounds__(256) gemm_tile(const _Float16* __restrict__ A,
                                                 const _Float16* __restrict__ B0,
                                                 float* __restrict__ C0, int n0t,
                                                 const _Float16* __restrict__ B1,
                                                 float* __restrict__ C1, int n1t,
                                                 const _Float16* __restrict__ B2,
                                                 float* __restrict__ C2, int n2t,
                                                 int Kd, int fuse,
                                                 const float* __restrict__ qw,
                                                 const float* __restrict__ kw,
                                                 const float* __restrict__ cosT,
                                                 const float* __restrict__ sinT,
                                                 _Float16* __restrict__ qH,
                                                 _Float16* __restrict__ img) {
    __shared__ _Float16 sA[2][128 * 32];
    __shared__ _Float16 sB[2][128 * 32];

    int tid = threadIdx.x;
    int w = tid >> 6, lane = tid & 63;
    int l15 = lane & 15, g4 = lane >> 4;
    int wm = w >> 1, wn = w & 1;

    int y = blockIdx.y;
    const _Float16* Bsel;
    float* Csel;
    int ldc, cb;
    if (y < n0t)            { Bsel = B0; Csel = C0; ldc = n0t * 128; cb = y; }
    else if (y < n0t + n1t) { Bsel = B1; Csel = C1; ldc = n1t * 128; cb = y - n0t; }
    else                    { Bsel = B2; Csel = C2; ldc = n2t * 128; cb = y - n0t - n1t; }

    const _Float16* Ab = A + (size_t)(blockIdx.x * 128) * Kd;
    const _Float16* Bb = Bsel + (size_t)(cb * 128) * Kd;

    int s0 = w * 128 + lane;
    int s1 = s0 + 64;
    size_t ga0 = (size_t)(s0 >> 2) * Kd + (s0 & 3) * 8;
    size_t ga1 = (size_t)(s1 >> 2) * Kd + (s1 & 3) * 8;

    #define STAGE(BUF, K0)                                                                     \
        do {                                                                                   \
            _Float16* a0_ = &sA[BUF][0] + (size_t)(w * 2) * 512;                               \
            _Float16* a1_ = &sA[BUF][0] + (size_t)(w * 2 + 1) * 512;                           \
            _Float16* b0_ = &sB[BUF][0] + (size_t)(w * 2) * 512;                               \
            _Float16* b1_ = &sB[BUF][0] + (size_t)(w * 2 + 1) * 512;                           \
            __builtin_amdgcn_global_load_lds(                                                  \
                (const __attribute__((address_space(1))) unsigned int*)(Ab + ga0 + (K0)),      \
                (__attribute__((address_space(3))) unsigned int*)a0_, 16, 0, 0);               \
            __builtin_amdgcn_global_load_lds(                                                  \
                (const __attribute__((address_space(1))) unsigned int*)(Ab + ga1 + (K0)),      \
                (__attribute__((address_space(3))) unsigned int*)a1_, 16, 0, 0);               \
            __builtin_amdgcn_global_load_lds(                                                  \
                (const __attribute__((address_space(1))) unsigned int*)(Bb + ga0 + (K0)),      \
                (__attribute__((address_space(3))) unsigned int*)b0_, 16, 0, 0);               \
            __builtin_amdgcn_global_load_lds(                                                  \
                (const __attribute__((address_space(1))) unsigned int*)(Bb + ga1 + (K0)),      \
                (__attribute__((address_space(3))) unsigned int*)b1_, 16, 0, 0);               \
        } while (0)

    f32x4 acc[4][4];
    #pragma unroll
    for (int i = 0; i < 4; i++)
        #pragma unroll
        for (int j = 0; j < 4; j++) acc[i][j] = (f32x4){0.f, 0.f, 0.f, 0.f};

    int nIt = Kd >> 5;
    STAGE(0, 0);
    if (nIt > 1) STAGE(1, 32);

    for (int it = 0; it < nIt; ++it) {
        int cur = it & 1;
        if (it + 1 < nIt) asm volatile("s_waitcnt vmcnt(4)" ::: "memory");
        else              asm volatile("s_waitcnt vmcnt(0)" ::: "memory");
        __builtin_amdgcn_sched_barrier(0);
        __builtin_amdgcn_s_barrier();          // all waves' tile-it loads landed
        __builtin_amdgcn_sched_barrier(0);

        half8 af[4], bf[4];
        #pragma unroll
        for (int mi = 0; mi < 4; mi++)
            af[mi] = *(const half8*)&sA[cur][(wm * 64 + mi * 16 + l15) * 32 + g4 * 8];
        #pragma unroll
        for (int ni = 0; ni < 4; ni++)
            bf[ni] = *(const half8*)&sB[cur][(wn * 64 + ni * 16 + l15) * 32 + g4 * 8];

        #pragma unroll
        for (int mi = 0; mi < 4; mi++)
            #pragma unroll
            for (int ni = 0; ni < 4; ni++)
                acc[mi][ni] = __builtin_amdgcn_mfma_f32_16x16x32_f16(af[mi], bf[ni], acc[mi][ni], 0, 0, 0);

        __builtin_amdgcn_sched_barrier(0);
        asm volatile("" ::: "memory");         // pin LDS reads above the barrier
        __builtin_amdgcn_s_barrier();          // all waves done reading buf[cur]
        __builtin_amdgcn_sched_barrier(0);
        if (it + 2 < nIt) STAGE(cur, (size_t)(it + 2) * 32);
    }
    #undef STAGE

    if (!fuse || y >= n0t + n1t) {
        // plain f32 C-write
        int rbase = blockIdx.x * 128 + wm * 64 + g4 * 4;
        int cbase = cb * 128 + wn * 64 + l15;
        #pragma unroll
        for (int mi = 0; mi < 4; mi++)
            #pragma unroll
            for (int r = 0; r < 4; r++) {
                float* crow = Csel + (size_t)(rbase + mi * 16 + r) * ldc + cbase;
                #pragma unroll
                for (int ni = 0; ni < 4; ni++) crow[ni * 16] = acc[mi][ni][r];
            }
        return;
    }

    // ---- fused rmsnorm+rope epilogue for Q (y<n0t) and K (n0t<=y<n0t+n1t) ----
    bool isQ = (y < n0t);
    const float* wv = isQ ? qw : kw;
    float* sC = (float*)&sA[0][0];     // staging LDS dead: 32 KB = [64][128] f32

    #pragma unroll
    for (int ch = 0; ch < 2; ch++) {
        __syncthreads();               // previous chunk's reads done / main loop done
        if (wm == ch) {
            #pragma unroll
            for (int mi = 0; mi < 4; mi++)
                #pragma unroll
                for (int ni = 0; ni < 4; ni++)
                    #pragma unroll
                    for (int r = 0; r < 4; r++)
                        sC[(mi * 16 + g4 * 4 + r) * 128 + wn * 64 + ni * 16 + l15] = acc[mi][ni][r];
        }
        __syncthreads();
        // each wave norms 16 rows of this 64-row chunk
        #pragma unroll
        for (int i = 0; i < 16; i++) {
            int rloc = w * 16 + i;
            int grow = blockIdx.x * 128 + ch * 64 + rloc;   // global row = b*T + t
            int t = grow & (T_ - 1);
            float x0 = sC[rloc * 128 + lane];
            float x1 = sC[rloc * 128 + lane + 64];
            float ss = x0 * x0 + x1 * x1;
            #pragma unroll
            for (int off = 1; off < 64; off <<= 1) ss += __shfl_xor(ss, off);
            float inv = rsqrtf(ss * (1.0f / 128.0f) + 1e-6f);
            float n0 = x0 * inv * wv[lane];
            float n1 = x1 * inv * wv[lane + 64];
            float c = cosT[t * 64 + lane];
            float s = sinT[t * 64 + lane];
            float r0 = n0 * c - n1 * s;
            float r1 = n1 * c + n0 * s;
            if (isQ) {
                _Float16* qrow = qH + (size_t)grow * (H_ * HD_) + cb * HD_;
                qrow[lane]      = (_Float16)(r0 * (1.0f / 128.0f));
                qrow[lane + 64] = (_Float16)(r1 * (1.0f / 128.0f));
            } else {
                int b = grow >> 11;                 // grow / T_
                int bid = (b * 4 + cb) * 32 + (t >> 6);
                _Float16* kout = img + (size_t)bid * (KV_TILE_BYTES / 2) + (t & 63) * KROW_F16;
                kout[lane]      = (_Float16)r0;
                kout[lane + 64] = (_Float16)r1;
            }
        }
    }
}

// ---------------- V-transpose pack into KV image V-part (256 records) ----------------
__global__ void __launch_bounds__(256) pack_v(const float* __restrict__ vf,
                                              _Float16* __restrict__ img) {
    int vb = blockIdx.x;
    int tile = vb & 31, g = (vb >> 5) & 3, b = vb >> 7;
    int tid = threadIdx.x;
    _Float16* out = img + (size_t)vb * (KV_TILE_BYTES / 2);
    #pragma unroll
    for (int it = 0; it < 5; it++) {
        int vi = tid + 256 * it;
        if (vi < 128 * 9) {
            int d = vi / 9, gr = vi % 9;
            half8 hv = (half8){0, 0, 0, 0, 0, 0, 0, 0};
            if (gr < 8) {
                const float* src = vf + ((size_t)((b * T_ + tile * 64 + gr * 8) * G_ + g)) * HD_ + d;
                #pragma unroll
                for (int j = 0; j < 8; j++) hv[j] = (_Float16)src[(size_t)j * (G_ * HD_)];
            }
            *(half8*)(out + VBASE_F16 + (size_t)vi * 8) = hv;
        }
    }
}

// ---------------- causal GQA flash attention v5 (R9-exact, measured 73.3 us) ----------------
__global__ void __launch_bounds__(256, 2) attn_mfma5(const _Float16* __restrict__ qh,
                                                     const _Float16* __restrict__ kvimg,
                                                     _Float16* __restrict__ ctx) {
    int id = blockIdx.x;
    int hlf = id >> 8, rr0 = id & 255;
    int qb = hlf ? (15 - (rr0 & 15)) : (rr0 & 15);
    int hb = (rr0 >> 4) | (hlf << 4);
    int h = hb & 15, b = hb >> 4;
    int g = h >> 2;

    int tid = threadIdx.x;
    int w = tid >> 6, lane = tid & 63;
    int l31 = lane & 31, hi = lane >> 5;

    __shared__ __align__(16) char sKV[2][KV_TILE_BYTES];

    int qW = qb * 128 + w * 32;
    int qme = qW + l31;

    half8 qfrag[8];
    {
        const _Float16* qrow = qh + ((size_t)(b * T_ + qme)) * (H_ * HD_) + h * HD_ + hi * 8;
        #pragma unroll
        for (int ks = 0; ks < 8; ks++) qfrag[ks] = *(const half8*)(qrow + ks * 16);
    }

    f32x16 o[4];
    #pragma unroll
    for (int dt2 = 0; dt2 < 4; dt2++)
        #pragma unroll
        for (int r = 0; r < 16; r++) o[dt2][r] = 0.f;
    float m = -INFINITY, lsum = 0.f;

    const char* ibase = (const char*)kvimg + (size_t)((b * 4 + g) * 32) * KV_TILE_BYTES;

    // 36 groups of 1024B per tile; wave w takes groups w, w+4, ..., w+32 (9 each)
    #define STAGE_T(BUF, KT)                                                                       \
        do {                                                                                       \
            const char* src_ = ibase + (size_t)(KT) * KV_TILE_BYTES;                               \
            char* dst_ = &sKV[BUF][0];                                                             \
            _Pragma("unroll")                                                                      \
            for (int i_ = 0; i_ < 9; i_++) {                                                       \
                int c_ = w + 4 * i_;                                                               \
                __builtin_amdgcn_global_load_lds(                                                  \
                    (const __attribute__((address_space(1))) unsigned int*)(src_ + c_ * 1024 + lane * 16), \
                    (__attribute__((address_space(3))) unsigned int*)(dst_ + c_ * 1024 + lane * 16), 16, 0, 0); \
            }                                                                                      \
        } while (0)

    int nt = 2 * qb + 2;
    int ktmax_w = (qW + 31) >> 6;

    STAGE_T(0, 0);
    STAGE_T(1, 1);      // nt >= 2 always

    for (int kt = 0; kt < nt; kt++) {
        int cur = kt & 1;
        if (kt + 1 < nt) asm volatile("s_waitcnt vmcnt(9)" ::: "memory");
        else             asm volatile("s_waitcnt vmcnt(0)" ::: "memory");
        __builtin_amdgcn_sched_barrier(0);
        __builtin_amdgcn_s_barrier();      // all waves' tile-kt loads landed
        __builtin_amdgcn_sched_barrier(0);

        if (kt <= ktmax_w) {
            const char* bufK = &sKV[cur][0];
            const char* bufV = &sKV[cur][0] + VBASE_F16 * 2;

            f32x16 stc[2];
            #pragma unroll
            for (int kt2 = 0; kt2 < 2; kt2++)
                #pragma unroll
                for (int r = 0; r < 16; r++) stc[kt2][r] = 0.f;

            __builtin_amdgcn_s_setprio(1);
            #pragma unroll
            for (int ks = 0; ks < 8; ks++) {
                #pragma unroll
                for (int kt2 = 0; kt2 < 2; kt2++) {
                    half8 kfr = *(const half8*)(bufK + (kt2 * 32 + l31) * (KROW_F16 * 2) + ks * 32 + hi * 16);
                    stc[kt2] = __builtin_amdgcn_mfma_f32_32x32x16_f16(kfr, qfrag[ks], stc[kt2], 0, 0, 0);
                }
            }
            __builtin_amdgcn_s_setprio(0);

            #pragma unroll
            for (int kt2 = 0; kt2 < 2; kt2++)
                #pragma unroll
                for (int reg = 0; reg < 16; reg++) {
                    int key = kt * 64 + kt2 * 32 + 8 * (reg >> 2) + 4 * hi + (reg & 3);
                    float v = stc[kt2][reg];
                    stc[kt2][reg] = (key <= qme) ? v : -INFINITY;
                }

            float pmax = -INFINITY;
            #pragma unroll
            for (int kt2 = 0; kt2 < 2; kt2++)
                #pragma unroll
                for (int reg = 0; reg < 16; reg++) pmax = fmaxf(pmax, stc[kt2][reg]);
            pmax = fmaxf(pmax, __shfl_xor(pmax, 32));

            if (__any(!(pmax - m <= 8.0f))) {
                float nm = fmaxf(m, pmax);
                float alpha = __expf(m - nm);
                lsum *= alpha;
                #pragma unroll
                for (int reg = 0; reg < 16; reg++) {
                    float ar = __shfl(alpha, 8 * (reg >> 2) + 4 * hi + (reg & 3));
                    #pragma unroll
                    for (int dt2 = 0; dt2 < 4; dt2++) o[dt2][reg] *= ar;
                }
                m = nm;
            }

            float rsum = 0.f;
            #pragma unroll
            for (int kt2 = 0; kt2 < 2; kt2++)
                #pragma unroll
                for (int reg = 0; reg < 16; reg++) {
                    float e = __expf(stc[kt2][reg] - m);
                    stc[kt2][reg] = e;
                    rsum += e;
                }
            rsum += __shfl_xor(rsum, 32);
            lsum += rsum;

            int pk[16];
            #pragma unroll
            for (int kt2 = 0; kt2 < 2; kt2++)
                #pragma unroll
                for (int oo = 0; oo < 4; oo++)
                    #pragma unroll
                    for (int c = 0; c < 2; c++) {
                        half2_t hp;
                        hp[0] = (_Float16)stc[kt2][4 * oo + 2 * c];
                        hp[1] = (_Float16)stc[kt2][4 * oo + 2 * c + 1];
                        pk[kt2 * 8 + 2 * oo + c] = __builtin_bit_cast(int, hp);
                    }

            __builtin_amdgcn_s_setprio(1);
            #pragma unroll
            for (int ks = 0; ks < 4; ks++) {
                int base = (ks >> 1) * 8 + (ks & 1) * 4;
                int z0 = hi ? pk[base + 0] : pk[base + 2];
                int z1 = hi ? pk[base + 1] : pk[base + 3];
                int xz0 = __shfl_xor(z0, 32);
                int xz1 = __shfl_xor(z1, 32);
                int4_t pi;
                pi[0] = hi ? xz0 : pk[base + 0];
                pi[1] = hi ? xz1 : pk[base + 1];
                pi[2] = hi ? pk[base + 2] : xz0;
                pi[3] = hi ? pk[base + 3] : xz1;
                half8 pfrag = __builtin_bit_cast(half8, pi);
                #pragma unroll
                for (int dt2 = 0; dt2 < 4; dt2++) {
                    half8 vfr = *(const half8*)(bufV + (dt2 * 32 + l31) * (VROW_F16 * 2) + ks * 32 + hi * 16);
                    o[dt2] = __builtin_amdgcn_mfma_f32_32x32x16_f16(pfrag, vfr, o[dt2], 0, 0, 0);
                }
            }
            __builtin_amdgcn_s_setprio(0);
        }

        __builtin_amdgcn_sched_barrier(0);
        asm volatile("" ::: "memory");     // pin LDS reads above the barrier
        __builtin_amdgcn_s_barrier();      // all waves done reading buf[cur]
        __builtin_amdgcn_sched_barrier(0);
        if (kt + 2 < nt) STAGE_T(cur, kt + 2);
    }
    #undef STAGE_T

    float invl = 1.0f / lsum;
    #pragma unroll
    for (int reg = 0; reg < 16; reg++) {
        int qrow = 8 * (reg >> 2) + 4 * hi + (reg & 3);
        float ir = __shfl(invl, qrow);
        _Float16* orow = ctx + (size_t)(b * T_ + qW + qrow) * (H_ * HD_) + h * HD_ + l31;
        #pragma unroll
        for (int dt2 = 0; dt2 < 4; dt2++)
            orow[dt2 * 32] = (_Float16)(o[dt2][reg] * ir);
    }
}

// ---------------- launch ----------------
extern "C" void kernel_launch(void* const* d_in, const int* in_sizes, int n_in,
                              void* d_out, int out_size, void* d_ws, size_t ws_size,
                              hipStream_t stream) {
    const float* x   = (const float*)d_in[0];
    const float* Wq  = (const float*)d_in[1];
    const float* Wk  = (const float*)d_in[2];
    const float* Wv  = (const float*)d_in[3];
    const float* Wo  = (const float*)d_in[4];
    const float* qnw = (const float*)d_in[5];
    const float* knw = (const float*)d_in[6];
    float* out = (float*)d_out;

    char* ws = (char*)d_ws;
    size_t off = 0;
    auto alloc = [&](size_t bytes) {
        char* p = ws + off;
        off += (bytes + 255) & ~(size_t)255;
        return p;
    };
    _Float16* x_h  = (_Float16*)alloc((size_t)B_ * T_ * D_ * 2);        // reused as q_h
    _Float16* wq_h = (_Float16*)alloc((size_t)H_ * HD_ * D_ * 2);       // reused as kvimg (with wk_h)
    _Float16* wk_h = (_Float16*)alloc((size_t)G_ * HD_ * D_ * 2);
    _Float16* wv_h = (_Float16*)alloc((size_t)G_ * HD_ * D_ * 2);
    _Float16* wo_h = (_Float16*)alloc((size_t)D_ * H_ * HD_ * 2);
    float* v_f = (float*)alloc((size_t)B_ * T_ * G_ * HD_ * 4);
    _Float16* ctx_h = (_Float16*)alloc((size_t)B_ * T_ * H_ * HD_ * 2);
    float* cosT = (float*)alloc((size_t)T_ * 64 * 4);
    float* sinT = (float*)alloc((size_t)T_ * 64 * 4);
    _Float16* q_h = (_Float16*)alloc((size_t)B_ * T_ * H_ * HD_ * 2);   // separate (x_h still live during QKV GEMM)
    _Float16* kvimg = (_Float16*)alloc((size_t)256 * KV_TILE_BYTES);

    // fused conversions + rope tables (one dispatch)
    cvt_rope<<<2560, 256, 0, stream>>>(x, Wq, Wk, Wv, Wo, x_h, wq_h, wk_h, wv_h, wo_h,
                                       cosT, sinT);

    // fused Q+K+V projection with in-epilogue rmsnorm+rope:
    // Q -> q_h (f16, 1/128), K -> kvimg K-part (f16), V -> v_f (f32)
    gemm_tile<<<dim3(32, 24), 256, 0, stream>>>(x_h, wq_h, nullptr, 16,
                                                wk_h, nullptr, 4,
                                                wv_h, v_f, 4, D_, 1,
                                                qnw, knw, cosT, sinT, q_h, kvimg);

    // V-transpose pack into KV image (256 records)
    pack_v<<<256, 256, 0, stream>>>(v_f, kvimg);

    // causal GQA attention -> ctx (f16)
    attn_mfma5<<<512, 256, 0, stream>>>(q_h, kvimg, ctx_h);

    // output projection: plain epilogue
    gemm_tile<<<dim3(32, 16), 256, 0, stream>>>(ctx_h, wo_h, out, 16,
                                                nullptr, nullptr, 0,
                                                nullptr, nullptr, 0, H_ * HD_, 0,
                                                nullptr, nullptr, nullptr, nullptr,
                                                nullptr, nullptr);
}